// Round 2
// baseline (1390.406 us; speedup 1.0000x reference)
//
#include <hip/hip_runtime.h>

#define NB 4
#define SEQ 1024
#define DM 1024
#define NH 16
#define DEP 64
#define DFFN 4096

typedef __attribute__((ext_vector_type(8))) short short8;
typedef __attribute__((ext_vector_type(4))) float f32x4;
typedef __attribute__((ext_vector_type(4))) unsigned short us4;

__device__ __forceinline__ unsigned short f2bf(float f) {
    union { float f; unsigned int u; } v; v.f = f;
    unsigned int u = v.u;
    return (unsigned short)((u + 0x7FFFu + ((u >> 16) & 1u)) >> 16);
}

// ---------------- strided cast f32 -> bf16 ----------------
// src is (rows, ncols) row-major; dst has leading dim dstld (elements).
__global__ __launch_bounds__(256) void cast_w_kernel(const float* __restrict__ in,
                                                     unsigned short* __restrict__ out,
                                                     int n4, int cper, int dstld) {
    int i = blockIdx.x * 256 + threadIdx.x;
    if (i < n4) {
        int r = i / cper, c4 = (i - r * cper) * 4;
        float4 f = *(const float4*)(in + (size_t)r * (cper * 4) + c4);
        us4 u;
        u[0] = f2bf(f.x); u[1] = f2bf(f.y); u[2] = f2bf(f.z); u[3] = f2bf(f.w);
        *(us4*)(out + (size_t)r * dstld + c4) = u;
    }
}

// ---------------- generic bf16 GEMM: C = A(MxK) @ W(KxN') + bias ----------------
// BMx128 tile, BK=32, 4 waves, mfma_f32_16x16x32_bf16. N = C leading dim; grid.x covers Ncols/128.
template <int BM, int RELU, int WB, int WF>
__global__ __launch_bounds__(256) void gemm_kernel(const unsigned short* __restrict__ A,
                                                   const unsigned short* __restrict__ W,
                                                   const float* __restrict__ bias,
                                                   unsigned short* __restrict__ Cb,
                                                   float* __restrict__ Cf,
                                                   int M, int N, int K) {
    constexpr int AM = BM / 32;   // acc row-tiles per wave
    constexpr int WR = BM / 2;    // wave row span
    __shared__ unsigned short As[BM][40];
    __shared__ unsigned short Bs[128][40];  // transposed: Bs[n][k]
    const int t = threadIdx.x;
    const int lane = t & 63, w = t >> 6;
    const int m0 = blockIdx.y * BM, n0 = blockIdx.x * 128;
    const int wm = (w >> 1) * WR, wn = (w & 1) * 64;
    const int lr = lane & 15, kb = (lane >> 4) * 8;

    f32x4 acc[AM][4];
#pragma unroll
    for (int a = 0; a < AM; ++a)
#pragma unroll
        for (int b = 0; b < 4; ++b)
#pragma unroll
            for (int j = 0; j < 4; ++j) acc[a][b][j] = 0.f;

    for (int kt = 0; kt < K; kt += 32) {
        __syncthreads();
        // stage A tile BMx32
#pragma unroll
        for (int p = 0; p < BM / 64; ++p) {
            int idx = p * 256 + t;
            int r = idx >> 2, c8 = (idx & 3) * 8;
            short8 v = *(const short8*)(A + (size_t)(m0 + r) * K + kt + c8);
            *(short8*)&As[r][c8] = v;
        }
        // stage W tile 32x128, transposed into Bs[n][k]
#pragma unroll
        for (int p = 0; p < 2; ++p) {
            int idx = p * 256 + t;
            int kk = idx >> 4, nn8 = (idx & 15) * 8;
            short8 v = *(const short8*)(W + (size_t)(kt + kk) * N + n0 + nn8);
#pragma unroll
            for (int j = 0; j < 8; ++j) Bs[nn8 + j][kk] = (unsigned short)v[j];
        }
        __syncthreads();

        short8 af[AM], bfr[4];
#pragma unroll
        for (int i = 0; i < AM; ++i) af[i] = *(const short8*)&As[wm + i * 16 + lr][kb];
#pragma unroll
        for (int i = 0; i < 4; ++i) bfr[i] = *(const short8*)&Bs[wn + i * 16 + lr][kb];
#pragma unroll
        for (int am = 0; am < AM; ++am)
#pragma unroll
            for (int bn = 0; bn < 4; ++bn)
                acc[am][bn] = __builtin_amdgcn_mfma_f32_16x16x32_bf16(af[am], bfr[bn], acc[am][bn], 0, 0, 0);
    }

#pragma unroll
    for (int am = 0; am < AM; ++am) {
#pragma unroll
        for (int bn = 0; bn < 4; ++bn) {
            int col = n0 + wn + bn * 16 + lr;
            float bv = bias ? bias[col] : 0.f;
#pragma unroll
            for (int i = 0; i < 4; ++i) {
                int row = m0 + wm + am * 16 + (lane >> 4) * 4 + i;
                float v = acc[am][bn][i] + bv;
                if (RELU) v = v > 0.f ? v : 0.f;
                if (WF) Cf[(size_t)row * N + col] = v;
                if (WB) Cb[(size_t)row * N + col] = f2bf(v);
            }
        }
    }
}

// ---------------- fused QK^T + softmax ----------------
// grid: (SEQ/16, B*NH). Block: 16 q-rows x all 1024 k-cols, probs f32 out.
template <int CAUSAL>
__global__ __launch_bounds__(256) void qksm_kernel(const unsigned short* __restrict__ Q, int ldq,
                                                   const unsigned short* __restrict__ Kp, int ldk,
                                                   const float* __restrict__ pad,
                                                   float* __restrict__ out) {
    __shared__ unsigned short Ks[256][72];
    __shared__ float red[4][16];
    const int t = threadIdx.x, lane = t & 63, w = t >> 6;
    const int lr = lane & 15, g = lane >> 4;
    const int q0 = blockIdx.x * 16;
    const int bh = blockIdx.y, b = bh >> 4, h = bh & 15;
    const size_t qbase = (size_t)b * SEQ * ldq + h * DEP;
    const size_t kbase = (size_t)b * SEQ * ldk + h * DEP;

    // Q fragments direct from global: row q0+lr, depth-slice ks*32 + g*8
    short8 aq[2];
#pragma unroll
    for (int ks = 0; ks < 2; ++ks)
        aq[ks] = *(const short8*)(Q + qbase + (size_t)(q0 + lr) * ldq + ks * 32 + g * 8);

    f32x4 acc[4][4];  // [k-chunk][col-tile]
#pragma unroll
    for (int a = 0; a < 4; ++a)
#pragma unroll
        for (int b2 = 0; b2 < 4; ++b2)
#pragma unroll
            for (int j = 0; j < 4; ++j) acc[a][b2][j] = 0.f;

    for (int kc = 0; kc < 4; ++kc) {
        __syncthreads();
        // stage K rows [kc*256, kc*256+256) x 64 depth
#pragma unroll
        for (int p = 0; p < 8; ++p) {
            int idx = p * 256 + t;
            int r = idx >> 3, c8 = (idx & 7) * 8;
            *(short8*)&Ks[r][c8] = *(const short8*)(Kp + kbase + (size_t)(kc * 256 + r) * ldk + c8);
        }
        __syncthreads();
#pragma unroll
        for (int ks = 0; ks < 2; ++ks) {
            short8 bk[4];
#pragma unroll
            for (int bn = 0; bn < 4; ++bn)
                bk[bn] = *(const short8*)&Ks[w * 64 + bn * 16 + lr][ks * 32 + g * 8];
#pragma unroll
            for (int bn = 0; bn < 4; ++bn)
                acc[kc][bn] = __builtin_amdgcn_mfma_f32_16x16x32_bf16(aq[ks], bk[bn], acc[kc][bn], 0, 0, 0);
        }
    }

    // scale + mask; element (kc,bn,i): row = q0 + g*4 + i, col = kc*256 + w*64 + bn*16 + lr
#pragma unroll
    for (int kc = 0; kc < 4; ++kc)
#pragma unroll
        for (int bn = 0; bn < 4; ++bn) {
            int col = kc * 256 + w * 64 + bn * 16 + lr;
            float pm = pad ? pad[(size_t)b * SEQ + col] * -1e9f : 0.f;
#pragma unroll
            for (int i = 0; i < 4; ++i) {
                int row = q0 + g * 4 + i;
                float v = acc[kc][bn][i] * 0.125f + pm;
                if (CAUSAL && col > row) v -= 1e9f;
                acc[kc][bn][i] = v;
            }
        }

    // row max (per lane: rows g*4+i over its 16 cols; then over lr group; then over waves)
    float m[4];
#pragma unroll
    for (int i = 0; i < 4; ++i) {
        float mm = -1e30f;
#pragma unroll
        for (int kc = 0; kc < 4; ++kc)
#pragma unroll
            for (int bn = 0; bn < 4; ++bn) mm = fmaxf(mm, acc[kc][bn][i]);
        m[i] = mm;
    }
#pragma unroll
    for (int d = 1; d < 16; d <<= 1)
#pragma unroll
        for (int i = 0; i < 4; ++i) m[i] = fmaxf(m[i], __shfl_xor(m[i], d));
    if (lr == 0)
#pragma unroll
        for (int i = 0; i < 4; ++i) red[w][g * 4 + i] = m[i];
    __syncthreads();
    float M[4];
#pragma unroll
    for (int i = 0; i < 4; ++i)
        M[i] = fmaxf(fmaxf(red[0][g * 4 + i], red[1][g * 4 + i]),
                     fmaxf(red[2][g * 4 + i], red[3][g * 4 + i]));
    __syncthreads();

    // exp + sum
    float s[4] = {0.f, 0.f, 0.f, 0.f};
#pragma unroll
    for (int kc = 0; kc < 4; ++kc)
#pragma unroll
        for (int bn = 0; bn < 4; ++bn)
#pragma unroll
            for (int i = 0; i < 4; ++i) {
                float e = __expf(acc[kc][bn][i] - M[i]);
                acc[kc][bn][i] = e;
                s[i] += e;
            }
#pragma unroll
    for (int d = 1; d < 16; d <<= 1)
#pragma unroll
        for (int i = 0; i < 4; ++i) s[i] += __shfl_xor(s[i], d);
    if (lr == 0)
#pragma unroll
        for (int i = 0; i < 4; ++i) red[w][g * 4 + i] = s[i];
    __syncthreads();
    float inv[4];
#pragma unroll
    for (int i = 0; i < 4; ++i)
        inv[i] = 1.0f / (red[0][g * 4 + i] + red[1][g * 4 + i] + red[2][g * 4 + i] + red[3][g * 4 + i]);

    // write probs
#pragma unroll
    for (int kc = 0; kc < 4; ++kc)
#pragma unroll
        for (int bn = 0; bn < 4; ++bn) {
            int col = kc * 256 + w * 64 + bn * 16 + lr;
#pragma unroll
            for (int i = 0; i < 4; ++i) {
                int row = q0 + g * 4 + i;
                out[((size_t)bh * SEQ + row) * SEQ + col] = acc[kc][bn][i] * inv[i];
            }
        }
}

// ---------------- PV: ctx = P(f32) @ V, per (b,h) ----------------
__global__ __launch_bounds__(256) void pv_kernel(const float* __restrict__ P,
                                                 const unsigned short* __restrict__ V, int ldv,
                                                 unsigned short* __restrict__ ctx) {
    __shared__ unsigned short Ps[128][40];
    __shared__ unsigned short Vs[64][40];  // Vs[dep][k]
    const int t = threadIdx.x, lane = t & 63, w = t >> 6;
    const int q0 = blockIdx.x * 128;
    const int b = blockIdx.y >> 4, h = blockIdx.y & 15;
    const float* Pb = P + ((size_t)blockIdx.y << 20);
    const unsigned short* Vb = V + (size_t)b * SEQ * ldv + h * DEP;
    const int wm = w * 32, lr = lane & 15, kb = (lane >> 4) * 8;

    f32x4 acc[2][4];
#pragma unroll
    for (int a = 0; a < 2; ++a)
#pragma unroll
        for (int b2 = 0; b2 < 4; ++b2)
#pragma unroll
            for (int j = 0; j < 4; ++j) acc[a][b2][j] = 0.f;

    for (int kt = 0; kt < SEQ; kt += 32) {
        __syncthreads();
#pragma unroll
        for (int p = 0; p < 4; ++p) {
            int id = p * 256 + t;
            int r = id >> 3, c4 = (id & 7) * 4;
            float4 f = *(const float4*)(Pb + (size_t)(q0 + r) * SEQ + kt + c4);
            us4 u;
            u[0] = f2bf(f.x); u[1] = f2bf(f.y); u[2] = f2bf(f.z); u[3] = f2bf(f.w);
            *(us4*)&Ps[r][c4] = u;
        }
        {
            int r = t >> 3, c8 = (t & 7) * 8;
            short8 v = *(const short8*)(Vb + (size_t)(kt + r) * ldv + c8);
#pragma unroll
            for (int j = 0; j < 8; ++j) Vs[c8 + j][r] = (unsigned short)v[j];
        }
        __syncthreads();

        short8 af[2], bfr[4];
#pragma unroll
        for (int i = 0; i < 2; ++i) af[i] = *(const short8*)&Ps[wm + i * 16 + lr][kb];
#pragma unroll
        for (int i = 0; i < 4; ++i) bfr[i] = *(const short8*)&Vs[i * 16 + lr][kb];
#pragma unroll
        for (int am = 0; am < 2; ++am)
#pragma unroll
            for (int bn = 0; bn < 4; ++bn)
                acc[am][bn] = __builtin_amdgcn_mfma_f32_16x16x32_bf16(af[am], bfr[bn], acc[am][bn], 0, 0, 0);
    }

#pragma unroll
    for (int am = 0; am < 2; ++am) {
#pragma unroll
        for (int bn = 0; bn < 4; ++bn) {
            int dep = bn * 16 + lr;
#pragma unroll
            for (int i = 0; i < 4; ++i) {
                int gq = q0 + wm + am * 16 + (lane >> 4) * 4 + i;
                ctx[((size_t)b * SEQ + gq) * DM + h * DEP + dep] = f2bf(acc[am][bn][i]);
            }
        }
    }
}

// ---------------- residual + layernorm: out = LN(X + R) ----------------
template <int WB>
__global__ __launch_bounds__(256) void ln_kernel(const float* __restrict__ X,
                                                 const float* __restrict__ R,
                                                 const float* __restrict__ gamma,
                                                 const float* __restrict__ beta,
                                                 float* __restrict__ outF,
                                                 unsigned short* __restrict__ outB) {
    size_t row = blockIdx.x;
    const int t = threadIdx.x;
    float4 a = ((const float4*)(X + (row << 10)))[t];
    float4 r = ((const float4*)(R + (row << 10)))[t];
    float v0 = a.x + r.x, v1 = a.y + r.y, v2 = a.z + r.z, v3 = a.w + r.w;
    float s = v0 + v1 + v2 + v3;
    float q = v0 * v0 + v1 * v1 + v2 * v2 + v3 * v3;
#pragma unroll
    for (int off = 32; off; off >>= 1) {
        s += __shfl_down(s, off);
        q += __shfl_down(q, off);
    }
    __shared__ float rs[4], rq[4];
    if ((t & 63) == 0) { rs[t >> 6] = s; rq[t >> 6] = q; }
    __syncthreads();
    s = rs[0] + rs[1] + rs[2] + rs[3];
    q = rq[0] + rq[1] + rq[2] + rq[3];
    float mean = s * (1.0f / 1024.0f);
    float var = q * (1.0f / 1024.0f) - mean * mean;
    float inv = rsqrtf(var + 1e-6f);
    float g0 = gamma[t * 4], g1 = gamma[t * 4 + 1], g2 = gamma[t * 4 + 2], g3 = gamma[t * 4 + 3];
    float b0 = beta[t * 4], b1 = beta[t * 4 + 1], b2 = beta[t * 4 + 2], b3 = beta[t * 4 + 3];
    float o0 = (v0 - mean) * inv * g0 + b0;
    float o1 = (v1 - mean) * inv * g1 + b1;
    float o2 = (v2 - mean) * inv * g2 + b2;
    float o3 = (v3 - mean) * inv * g3 + b3;
    float4 o; o.x = o0; o.y = o1; o.z = o2; o.w = o3;
    ((float4*)(outF + (row << 10)))[t] = o;
    if (WB) {
        us4 u;
        u[0] = f2bf(o0); u[1] = f2bf(o1); u[2] = f2bf(o2); u[3] = f2bf(o3);
        ((us4*)(outB + (row << 10)))[t] = u;
    }
}

extern "C" void kernel_launch(void* const* d_in, const int* in_sizes, int n_in,
                              void* d_out, int out_size, void* d_ws, size_t ws_size,
                              hipStream_t stream) {
    const float* x = (const float*)d_in[0];
    const float* enc = (const float*)d_in[1];
    const float* pad = (const float*)d_in[3];
    const float* wq1 = (const float*)d_in[4];  const float* bq1 = (const float*)d_in[5];
    const float* wk1 = (const float*)d_in[6];  const float* bk1 = (const float*)d_in[7];
    const float* wv1 = (const float*)d_in[8];  const float* bv1 = (const float*)d_in[9];
    const float* wo1 = (const float*)d_in[10]; const float* bo1 = (const float*)d_in[11];
    const float* wq2 = (const float*)d_in[12]; const float* bq2 = (const float*)d_in[13];
    const float* wk2 = (const float*)d_in[14]; const float* bk2 = (const float*)d_in[15];
    const float* wv2 = (const float*)d_in[16]; const float* bv2 = (const float*)d_in[17];
    const float* wo2 = (const float*)d_in[18]; const float* bo2 = (const float*)d_in[19];
    const float* wf1 = (const float*)d_in[20]; const float* bf1 = (const float*)d_in[21];
    const float* wf2 = (const float*)d_in[22]; const float* bf2 = (const float*)d_in[23];
    const float* g1 = (const float*)d_in[24]; const float* be1 = (const float*)d_in[25];
    const float* g2 = (const float*)d_in[26]; const float* be2 = (const float*)d_in[27];
    const float* g3 = (const float*)d_in[28]; const float* be3 = (const float*)d_in[29];

    float* out3 = (float*)d_out;
    float* aw1 = out3 + (size_t)NB * SEQ * DM;
    float* aw2 = aw1 + (size_t)NB * NH * SEQ * SEQ;

    // ----- workspace arena -----
    char* ws = (char*)d_ws;
    size_t off = 0;
    auto take = [&](size_t n) { char* p = ws + off; off += (n + 255) & ~(size_t)255; return p; };
    const size_t SZ_SD_BF = (size_t)NB * SEQ * DM * 2;    // 8 MB
    const size_t SZ_SD_F  = (size_t)NB * SEQ * DM * 4;    // 16 MB

    unsigned short* wqkv1b = (unsigned short*)take((size_t)DM * 3 * DM * 2);  // (1024,3072)
    unsigned short* wq2b   = (unsigned short*)take((size_t)DM * DM * 2);
    unsigned short* wkv2b  = (unsigned short*)take((size_t)DM * 2 * DM * 2);  // (1024,2048)
    unsigned short* wo1b   = (unsigned short*)take((size_t)DM * DM * 2);
    unsigned short* wo2b   = (unsigned short*)take((size_t)DM * DM * 2);
    unsigned short* wf1b   = (unsigned short*)take((size_t)DM * DFFN * 2);
    unsigned short* wf2b   = (unsigned short*)take((size_t)DFFN * DM * 2);
    float* bqkv1 = (float*)take(3 * DM * 4);
    float* bkv2  = (float*)take(2 * DM * 4);
    unsigned short* xb    = (unsigned short*)take(SZ_SD_BF);
    unsigned short* encb  = (unsigned short*)take(SZ_SD_BF);
    unsigned short* qkv1b = (unsigned short*)take(3 * SZ_SD_BF);  // (4096,3072)
    unsigned short* qb    = (unsigned short*)take(SZ_SD_BF);
    unsigned short* kv2b  = (unsigned short*)take(2 * SZ_SD_BF);  // (4096,2048)
    unsigned short* ctx   = (unsigned short*)take(SZ_SD_BF);
    float* goutf = (float*)take(SZ_SD_F);
    float* out1f = (float*)take(SZ_SD_F);
    unsigned short* out1b = (unsigned short*)take(SZ_SD_BF);
    float* out2f = (float*)take(SZ_SD_F);
    unsigned short* out2b = (unsigned short*)take(SZ_SD_BF);
    unsigned short* ffn1b = (unsigned short*)take((size_t)NB * SEQ * DFFN * 2);

    // ----- casts (all via strided cast) -----
    auto castw = [&](const float* src, unsigned short* dst, size_t rows, int ncols, int dstld) {
        size_t n4 = rows * (size_t)ncols / 4;
        cast_w_kernel<<<(unsigned)((n4 + 255) / 256), 256, 0, stream>>>(src, dst, (int)n4, ncols / 4, dstld);
    };
    castw(x, xb, (size_t)NB * SEQ, DM, DM);
    castw(enc, encb, (size_t)NB * SEQ, DM, DM);
    castw(wq1, wqkv1b + 0,        DM, DM, 3 * DM);
    castw(wk1, wqkv1b + DM,       DM, DM, 3 * DM);
    castw(wv1, wqkv1b + 2 * DM,   DM, DM, 3 * DM);
    castw(wq2, wq2b, DM, DM, DM);
    castw(wk2, wkv2b + 0,  DM, DM, 2 * DM);
    castw(wv2, wkv2b + DM, DM, DM, 2 * DM);
    castw(wo1, wo1b, DM, DM, DM);
    castw(wo2, wo2b, DM, DM, DM);
    castw(wf1, wf1b, DM, DFFN, DFFN);
    castw(wf2, wf2b, DFFN, DM, DM);
    // concat biases (d2d async copies)
    hipMemcpyAsync(bqkv1,          bq1, DM * 4, hipMemcpyDeviceToDevice, stream);
    hipMemcpyAsync(bqkv1 + DM,     bk1, DM * 4, hipMemcpyDeviceToDevice, stream);
    hipMemcpyAsync(bqkv1 + 2 * DM, bv1, DM * 4, hipMemcpyDeviceToDevice, stream);
    hipMemcpyAsync(bkv2,           bk2, DM * 4, hipMemcpyDeviceToDevice, stream);
    hipMemcpyAsync(bkv2 + DM,      bv2, DM * 4, hipMemcpyDeviceToDevice, stream);

    const int M = NB * SEQ;  // 4096
    dim3 gQKV(3 * DM / 128, M / 128);   // 24x32 = 768
    dim3 gKV(2 * DM / 128, M / 128);    // 16x32 = 512
    dim3 gDD64(DM / 128, M / 64);       // 8x64 = 512
    dim3 gDF(DFFN / 128, M / 128);      // 32x32 = 1024
    dim3 gQS(SEQ / 16, NB * NH);        // 64x64 = 4096
    dim3 gPV(SEQ / 128, NB * NH);

    // ---- MHA1 (self, causal) ----
    gemm_kernel<128, 0, 1, 0><<<gQKV, 256, 0, stream>>>(xb, wqkv1b, bqkv1, qkv1b, nullptr, M, 3 * DM, DM);
    qksm_kernel<1><<<gQS, 256, 0, stream>>>(qkv1b, 3 * DM, qkv1b + DM, 3 * DM, nullptr, aw1);
    pv_kernel<<<gPV, 256, 0, stream>>>(aw1, qkv1b + 2 * DM, 3 * DM, ctx);
    gemm_kernel<64, 0, 0, 1><<<gDD64, 256, 0, stream>>>(ctx, wo1b, bo1, nullptr, goutf, M, DM, DM);
    ln_kernel<1><<<M, 256, 0, stream>>>(goutf, x, g1, be1, out1f, out1b);

    // ---- MHA2 (cross, padding mask) ----
    gemm_kernel<64, 0, 1, 0><<<gDD64, 256, 0, stream>>>(out1b, wq2b, bq2, qb, nullptr, M, DM, DM);
    gemm_kernel<128, 0, 1, 0><<<gKV, 256, 0, stream>>>(encb, wkv2b, bkv2, kv2b, nullptr, M, 2 * DM, DM);
    qksm_kernel<0><<<gQS, 256, 0, stream>>>(qb, DM, kv2b, 2 * DM, pad, aw2);
    pv_kernel<<<gPV, 256, 0, stream>>>(aw2, kv2b + DM, 2 * DM, ctx);
    gemm_kernel<64, 0, 0, 1><<<gDD64, 256, 0, stream>>>(ctx, wo2b, bo2, nullptr, goutf, M, DM, DM);
    ln_kernel<1><<<M, 256, 0, stream>>>(goutf, out1f, g2, be2, out2f, out2b);

    // ---- FFN ----
    gemm_kernel<128, 1, 1, 0><<<gDF, 256, 0, stream>>>(out2b, wf1b, bf1, ffn1b, nullptr, M, DFFN, DM);
    gemm_kernel<64, 0, 0, 1><<<gDD64, 256, 0, stream>>>(ffn1b, wf2b, bf2, nullptr, goutf, M, DM, DFFN);
    ln_kernel<0><<<M, 256, 0, stream>>>(goutf, out2f, g3, be3, out3, nullptr);
}

// Round 3
// 956.526 us; speedup vs baseline: 1.4536x; 1.4536x over previous
//
#include <hip/hip_runtime.h>

#define NB 4
#define SEQ 1024
#define DM 1024
#define NH 16
#define DEP 64
#define DFFN 4096

typedef __attribute__((ext_vector_type(8))) short short8;
typedef __attribute__((ext_vector_type(4))) float f32x4;
typedef __attribute__((ext_vector_type(4))) unsigned short us4;

__device__ __forceinline__ unsigned short f2bf(float f) {
    union { float f; unsigned int u; } v; v.f = f;
    unsigned int u = v.u;
    return (unsigned short)((u + 0x7FFFu + ((u >> 16) & 1u)) >> 16);
}

__device__ __forceinline__ void gload16(const void* g, void* l) {
    __builtin_amdgcn_global_load_lds((const __attribute__((address_space(1))) unsigned int*)g,
                                     (__attribute__((address_space(3))) unsigned int*)l, 16, 0, 0);
}

// ---------------- plain cast f32 -> bf16 (row-major, vectorized) ----------------
__global__ __launch_bounds__(256) void cast_bf16_kernel(const float* __restrict__ in,
                                                        unsigned short* __restrict__ out, int n4) {
    int i = blockIdx.x * 256 + threadIdx.x;
    if (i < n4) {
        float4 f = ((const float4*)in)[i];
        us4 u;
        u[0] = f2bf(f.x); u[1] = f2bf(f.y); u[2] = f2bf(f.z); u[3] = f2bf(f.w);
        ((us4*)out)[i] = u;
    }
}

// ---------------- transpose-cast: W (RxC f32) -> Wt (CxR bf16) ----------------
// grid: (C/64, R/64), block 256. LDS-tiled, coalesced both sides.
__global__ __launch_bounds__(256) void castT_kernel(const float* __restrict__ in,
                                                    unsigned short* __restrict__ out,
                                                    int R, int C) {
    __shared__ float tile[64][65];
    const int t = threadIdx.x;
    const int c0 = blockIdx.x * 64, r0 = blockIdx.y * 64;
#pragma unroll
    for (int p = 0; p < 4; ++p) {
        int r = p * 16 + (t >> 4), c = (t & 15) * 4;
        float4 f = *(const float4*)(in + (size_t)(r0 + r) * C + c0 + c);
        tile[r][c] = f.x; tile[r][c + 1] = f.y; tile[r][c + 2] = f.z; tile[r][c + 3] = f.w;
    }
    __syncthreads();
#pragma unroll
    for (int p = 0; p < 4; ++p) {
        int n = p * 16 + (t >> 4), k = (t & 15) * 4;
        us4 u;
#pragma unroll
        for (int j = 0; j < 4; ++j) u[j] = f2bf(tile[k + j][n]);
        *(us4*)(out + (size_t)(c0 + n) * R + r0 + k) = u;
    }
}

// ---------------- m97-style bf16 GEMM: C = A(MxK) @ Wt^T + bias ----------------
// A row-major [M][K]; Wt row-major [N][K] (pre-transposed weights).
// Tile BM x BN, BK=32, linear LDS staged via global_load_lds width=16.
template <int BM, int BN, int RELU, int WB, int WF, int WVT>
__global__ __launch_bounds__(256) void gemm_kernel(const unsigned short* __restrict__ A,
                                                   const unsigned short* __restrict__ Wt,
                                                   const float* __restrict__ bias,
                                                   unsigned short* __restrict__ Cb,
                                                   float* __restrict__ Cf,
                                                   unsigned short* __restrict__ Vt,
                                                   int vstart,
                                                   int M, int N, int K) {
    constexpr int AM = BM / 32;          // acc row-tiles per wave (2x2 wave grid)
    constexpr int AI = BM / 64;          // A gloads per wave
    constexpr int BI = BN / 64;          // B gloads per wave
    __shared__ unsigned short As[BM * 32];
    __shared__ unsigned short Bs[BN * 32];
    const int t = threadIdx.x;
    const int lane = t & 63, w = t >> 6;
    const int m0 = blockIdx.y * BM, n0 = blockIdx.x * BN;
    const int wm = (w >> 1) * (BM / 2), wn = (w & 1) * (BN / 2);
    const int lr = lane & 15, g = lane >> 4, kb = g * 8;
    const int srow = lane >> 2, scol = (lane & 3) * 8;

    f32x4 acc[AM][4];
#pragma unroll
    for (int a = 0; a < AM; ++a)
#pragma unroll
        for (int b = 0; b < 4; ++b)
#pragma unroll
            for (int j = 0; j < 4; ++j) acc[a][b][j] = 0.f;

    for (int kt = 0; kt < K; kt += 32) {
        __syncthreads();
#pragma unroll
        for (int ia = 0; ia < AI; ++ia) {
            int rb = w * (BM / 4) + ia * 16;
            gload16(A + (size_t)(m0 + rb + srow) * K + kt + scol, As + rb * 32);
        }
#pragma unroll
        for (int ib = 0; ib < BI; ++ib) {
            int rb = w * (BN / 4) + ib * 16;
            gload16(Wt + (size_t)(n0 + rb + srow) * K + kt + scol, Bs + rb * 32);
        }
        __syncthreads();

        short8 af[AM], bfr[4];
#pragma unroll
        for (int i = 0; i < AM; ++i) af[i] = *(const short8*)&As[(wm + i * 16 + lr) * 32 + kb];
#pragma unroll
        for (int i = 0; i < 4; ++i) bfr[i] = *(const short8*)&Bs[(wn + i * 16 + lr) * 32 + kb];
#pragma unroll
        for (int am = 0; am < AM; ++am)
#pragma unroll
            for (int bn = 0; bn < 4; ++bn)
                acc[am][bn] = __builtin_amdgcn_mfma_f32_16x16x32_bf16(af[am], bfr[bn], acc[am][bn], 0, 0, 0);
    }

#pragma unroll
    for (int am = 0; am < AM; ++am) {
#pragma unroll
        for (int bn = 0; bn < 4; ++bn) {
            int col = n0 + wn + bn * 16 + lr;
            float bv = bias ? bias[col] : 0.f;
            int rowb = m0 + wm + am * 16 + g * 4;
            float vv[4];
#pragma unroll
            for (int i = 0; i < 4; ++i) {
                float v = acc[am][bn][i] + bv;
                if (RELU) v = v > 0.f ? v : 0.f;
                vv[i] = v;
                if (WF) Cf[(size_t)(rowb + i) * N + col] = v;
                if (WB) Cb[(size_t)(rowb + i) * N + col] = f2bf(v);
            }
            if (WVT && col >= vstart) {
                int h = (col - vstart) >> 6, dep = (col - vstart) & 63;
                int b = rowb >> 10, kpos = rowb & 1023;
                us4 u;
#pragma unroll
                for (int i = 0; i < 4; ++i) u[i] = f2bf(vv[i]);
                *(us4*)(Vt + ((size_t)(b * NH + h) * DEP + dep) * SEQ + kpos) = u;
            }
        }
    }
}

// ---------------- fused attention: QK^T + mask + softmax + aw-write + PV ----------------
// grid: (SEQ/16, B*NH). Block: 16 q-rows x 1024 k. Vt is [B*NH][DEP][SEQ] bf16.
template <int CAUSAL>
__global__ __launch_bounds__(256) void attn_kernel(const unsigned short* __restrict__ Q, int ldq,
                                                   const unsigned short* __restrict__ Kp, int ldk,
                                                   const unsigned short* __restrict__ Vt,
                                                   const float* __restrict__ pad,
                                                   float* __restrict__ aw,
                                                   unsigned short* __restrict__ ctx) {
    __shared__ unsigned short Ks[256][72];
    __shared__ unsigned short Ps[16][1026];
    __shared__ float red[4][16];
    const int t = threadIdx.x, lane = t & 63, w = t >> 6;
    const int lr = lane & 15, g = lane >> 4;
    const int q0 = blockIdx.x * 16;
    const int bh = blockIdx.y, b = bh >> 4, h = bh & 15;
    const size_t qbase = (size_t)b * SEQ * ldq + (size_t)h * DEP;
    const size_t kbase = (size_t)b * SEQ * ldk + (size_t)h * DEP;
    const int kcmax = CAUSAL ? (q0 >> 8) + 1 : 4;

    short8 aq[2];
#pragma unroll
    for (int ks = 0; ks < 2; ++ks)
        aq[ks] = *(const short8*)(Q + qbase + (size_t)(q0 + lr) * ldq + ks * 32 + g * 8);

    f32x4 acc[4][4];
#pragma unroll
    for (int a = 0; a < 4; ++a)
#pragma unroll
        for (int b2 = 0; b2 < 4; ++b2)
#pragma unroll
            for (int j = 0; j < 4; ++j) acc[a][b2][j] = 0.f;

    // ---- QK^T over valid K chunks ----
    for (int kc = 0; kc < kcmax; ++kc) {
        __syncthreads();
#pragma unroll
        for (int p = 0; p < 8; ++p) {
            int idx = p * 256 + t;
            int r = idx >> 3, c8 = (idx & 7) * 8;
            *(short8*)&Ks[r][c8] = *(const short8*)(Kp + kbase + (size_t)(kc * 256 + r) * ldk + c8);
        }
        __syncthreads();
#pragma unroll
        for (int ks = 0; ks < 2; ++ks) {
            short8 bk[4];
#pragma unroll
            for (int bn = 0; bn < 4; ++bn)
                bk[bn] = *(const short8*)&Ks[w * 64 + bn * 16 + lr][ks * 32 + g * 8];
#pragma unroll
            for (int bn = 0; bn < 4; ++bn)
                acc[kc][bn] = __builtin_amdgcn_mfma_f32_16x16x32_bf16(aq[ks], bk[bn], acc[kc][bn], 0, 0, 0);
        }
    }

    // ---- scale + mask ----
    for (int kc = 0; kc < kcmax; ++kc)
#pragma unroll
        for (int bn = 0; bn < 4; ++bn) {
            int col = kc * 256 + w * 64 + bn * 16 + lr;
            float pm = pad ? pad[(size_t)b * SEQ + col] * -1e9f : 0.f;
#pragma unroll
            for (int i = 0; i < 4; ++i) {
                int row = q0 + g * 4 + i;
                float v = acc[kc][bn][i] * 0.125f + pm;
                if (CAUSAL && col > row) v -= 1e9f;
                acc[kc][bn][i] = v;
            }
        }

    // ---- row max ----
    float m[4] = {-1e30f, -1e30f, -1e30f, -1e30f};
    for (int kc = 0; kc < kcmax; ++kc)
#pragma unroll
        for (int bn = 0; bn < 4; ++bn)
#pragma unroll
            for (int i = 0; i < 4; ++i) m[i] = fmaxf(m[i], acc[kc][bn][i]);
#pragma unroll
    for (int d = 1; d < 16; d <<= 1)
#pragma unroll
        for (int i = 0; i < 4; ++i) m[i] = fmaxf(m[i], __shfl_xor(m[i], d));
    if (lr == 0)
#pragma unroll
        for (int i = 0; i < 4; ++i) red[w][g * 4 + i] = m[i];
    __syncthreads();
    float M[4];
#pragma unroll
    for (int i = 0; i < 4; ++i)
        M[i] = fmaxf(fmaxf(red[0][g * 4 + i], red[1][g * 4 + i]),
                     fmaxf(red[2][g * 4 + i], red[3][g * 4 + i]));
    __syncthreads();

    // ---- exp + sum ----
    float s[4] = {0.f, 0.f, 0.f, 0.f};
    for (int kc = 0; kc < kcmax; ++kc)
#pragma unroll
        for (int bn = 0; bn < 4; ++bn)
#pragma unroll
            for (int i = 0; i < 4; ++i) {
                float e = __expf(acc[kc][bn][i] - M[i]);
                acc[kc][bn][i] = e;
                s[i] += e;
            }
#pragma unroll
    for (int d = 1; d < 16; d <<= 1)
#pragma unroll
        for (int i = 0; i < 4; ++i) s[i] += __shfl_xor(s[i], d);
    if (lr == 0)
#pragma unroll
        for (int i = 0; i < 4; ++i) red[w][g * 4 + i] = s[i];
    __syncthreads();
    float inv[4];
#pragma unroll
    for (int i = 0; i < 4; ++i)
        inv[i] = 1.0f / (red[0][g * 4 + i] + red[1][g * 4 + i] + red[2][g * 4 + i] + red[3][g * 4 + i]);

    // ---- write aw (f32, mandatory) + Ps (bf16 in LDS) ----
#pragma unroll
    for (int kc = 0; kc < 4; ++kc)
#pragma unroll
        for (int bn = 0; bn < 4; ++bn) {
            int col = kc * 256 + w * 64 + bn * 16 + lr;
#pragma unroll
            for (int i = 0; i < 4; ++i) {
                int row = q0 + g * 4 + i;
                float p = (kc < kcmax) ? acc[kc][bn][i] * inv[i] : 0.f;
                aw[((size_t)bh * SEQ + row) * SEQ + col] = p;
                if (kc < kcmax) Ps[g * 4 + i][col] = f2bf(p);
            }
        }
    __syncthreads();

    // ---- PV: out(16 x 64) = P @ V, wave w handles dep-tile w; V^T read from global (L2-hot) ----
    const unsigned short* vb = Vt + ((size_t)bh * DEP + w * 16 + lr) * SEQ;
    f32x4 acc2;
#pragma unroll
    for (int j = 0; j < 4; ++j) acc2[j] = 0.f;
    for (int kc = 0; kc < kcmax; ++kc) {
#pragma unroll
        for (int k8 = 0; k8 < 8; ++k8) {
            int ks = kc * 8 + k8;
            short8 af = *(const short8*)&Ps[lr][ks * 32 + g * 8];
            short8 bf = *(const short8*)(vb + ks * 32 + g * 8);
            acc2 = __builtin_amdgcn_mfma_f32_16x16x32_bf16(af, bf, acc2, 0, 0, 0);
        }
    }
#pragma unroll
    for (int i = 0; i < 4; ++i)
        ctx[((size_t)b * SEQ + q0 + g * 4 + i) * DM + h * DEP + w * 16 + lr] = f2bf(acc2[i]);
}

// ---------------- residual + layernorm: out = LN(X + R) ----------------
template <int WB>
__global__ __launch_bounds__(256) void ln_kernel(const float* __restrict__ X,
                                                 const float* __restrict__ R,
                                                 const float* __restrict__ gamma,
                                                 const float* __restrict__ beta,
                                                 float* __restrict__ outF,
                                                 unsigned short* __restrict__ outB) {
    size_t row = blockIdx.x;
    const int t = threadIdx.x;
    float4 a = ((const float4*)(X + (row << 10)))[t];
    float4 r = ((const float4*)(R + (row << 10)))[t];
    float v0 = a.x + r.x, v1 = a.y + r.y, v2 = a.z + r.z, v3 = a.w + r.w;
    float s = v0 + v1 + v2 + v3;
    float q = v0 * v0 + v1 * v1 + v2 * v2 + v3 * v3;
#pragma unroll
    for (int off = 32; off; off >>= 1) {
        s += __shfl_down(s, off);
        q += __shfl_down(q, off);
    }
    __shared__ float rs[4], rq[4];
    if ((t & 63) == 0) { rs[t >> 6] = s; rq[t >> 6] = q; }
    __syncthreads();
    s = rs[0] + rs[1] + rs[2] + rs[3];
    q = rq[0] + rq[1] + rq[2] + rq[3];
    float mean = s * (1.0f / 1024.0f);
    float var = q * (1.0f / 1024.0f) - mean * mean;
    float inv = rsqrtf(var + 1e-6f);
    float g0 = gamma[t * 4], g1 = gamma[t * 4 + 1], g2 = gamma[t * 4 + 2], g3 = gamma[t * 4 + 3];
    float b0 = beta[t * 4], b1 = beta[t * 4 + 1], b2 = beta[t * 4 + 2], b3 = beta[t * 4 + 3];
    float o0 = (v0 - mean) * inv * g0 + b0;
    float o1 = (v1 - mean) * inv * g1 + b1;
    float o2 = (v2 - mean) * inv * g2 + b2;
    float o3 = (v3 - mean) * inv * g3 + b3;
    float4 o; o.x = o0; o.y = o1; o.z = o2; o.w = o3;
    ((float4*)(outF + (row << 10)))[t] = o;
    if (WB) {
        us4 u;
        u[0] = f2bf(o0); u[1] = f2bf(o1); u[2] = f2bf(o2); u[3] = f2bf(o3);
        ((us4*)(outB + (row << 10)))[t] = u;
    }
}

extern "C" void kernel_launch(void* const* d_in, const int* in_sizes, int n_in,
                              void* d_out, int out_size, void* d_ws, size_t ws_size,
                              hipStream_t stream) {
    const float* x = (const float*)d_in[0];
    const float* enc = (const float*)d_in[1];
    const float* pad = (const float*)d_in[3];
    const float* wq1 = (const float*)d_in[4];  const float* bq1 = (const float*)d_in[5];
    const float* wk1 = (const float*)d_in[6];  const float* bk1 = (const float*)d_in[7];
    const float* wv1 = (const float*)d_in[8];  const float* bv1 = (const float*)d_in[9];
    const float* wo1 = (const float*)d_in[10]; const float* bo1 = (const float*)d_in[11];
    const float* wq2 = (const float*)d_in[12]; const float* bq2 = (const float*)d_in[13];
    const float* wk2 = (const float*)d_in[14]; const float* bk2 = (const float*)d_in[15];
    const float* wv2 = (const float*)d_in[16]; const float* bv2 = (const float*)d_in[17];
    const float* wo2 = (const float*)d_in[18]; const float* bo2 = (const float*)d_in[19];
    const float* wf1 = (const float*)d_in[20]; const float* bf1 = (const float*)d_in[21];
    const float* wf2 = (const float*)d_in[22]; const float* bf2 = (const float*)d_in[23];
    const float* g1 = (const float*)d_in[24]; const float* be1 = (const float*)d_in[25];
    const float* g2 = (const float*)d_in[26]; const float* be2 = (const float*)d_in[27];
    const float* g3 = (const float*)d_in[28]; const float* be3 = (const float*)d_in[29];

    float* out3 = (float*)d_out;
    float* aw1 = out3 + (size_t)NB * SEQ * DM;
    float* aw2 = aw1 + (size_t)NB * NH * SEQ * SEQ;

    // ----- workspace arena -----
    char* ws = (char*)d_ws;
    size_t off = 0;
    auto take = [&](size_t n) { char* p = ws + off; off += (n + 255) & ~(size_t)255; return p; };
    const size_t SZ_SD_BF = (size_t)NB * SEQ * DM * 2;
    const size_t SZ_SD_F  = (size_t)NB * SEQ * DM * 4;
    const size_t SZ_DD_BF = (size_t)DM * DM * 2;

    unsigned short* wqkv1t = (unsigned short*)take(3 * SZ_DD_BF);  // [3072][1024]
    unsigned short* wq2t   = (unsigned short*)take(SZ_DD_BF);
    unsigned short* wkv2t  = (unsigned short*)take(2 * SZ_DD_BF);  // [2048][1024]
    unsigned short* wo1t   = (unsigned short*)take(SZ_DD_BF);
    unsigned short* wo2t   = (unsigned short*)take(SZ_DD_BF);
    unsigned short* wf1t   = (unsigned short*)take((size_t)DM * DFFN * 2);  // [4096][1024]
    unsigned short* wf2t   = (unsigned short*)take((size_t)DFFN * DM * 2);  // [1024][4096]
    float* bqkv1 = (float*)take(3 * DM * 4);
    float* bkv2  = (float*)take(2 * DM * 4);
    unsigned short* xb    = (unsigned short*)take(SZ_SD_BF);
    unsigned short* encb  = (unsigned short*)take(SZ_SD_BF);
    unsigned short* qkv1b = (unsigned short*)take(3 * SZ_SD_BF);   // [4096][3072]
    unsigned short* v1t   = (unsigned short*)take(SZ_SD_BF);       // [64][64][1024]
    unsigned short* qb    = (unsigned short*)take(SZ_SD_BF);
    unsigned short* kv2b  = (unsigned short*)take(2 * SZ_SD_BF);   // [4096][2048]
    unsigned short* v2t   = (unsigned short*)take(SZ_SD_BF);
    unsigned short* ctx   = (unsigned short*)take(SZ_SD_BF);
    float* goutf = (float*)take(SZ_SD_F);
    float* out1f = (float*)take(SZ_SD_F);
    unsigned short* out1b = (unsigned short*)take(SZ_SD_BF);
    float* out2f = (float*)take(SZ_SD_F);
    unsigned short* out2b = (unsigned short*)take(SZ_SD_BF);
    unsigned short* ffn1b = (unsigned short*)take((size_t)NB * SEQ * DFFN * 2);

    // ----- casts -----
    auto cast = [&](const float* src, unsigned short* dst, size_t n) {
        cast_bf16_kernel<<<(unsigned)((n / 4 + 255) / 256), 256, 0, stream>>>(src, dst, (int)(n / 4));
    };
    auto castT = [&](const float* src, unsigned short* dst, int R, int C) {
        dim3 gr(C / 64, R / 64);
        castT_kernel<<<gr, 256, 0, stream>>>(src, dst, R, C);
    };
    cast(x, xb, (size_t)NB * SEQ * DM);
    cast(enc, encb, (size_t)NB * SEQ * DM);
    castT(wq1, wqkv1t,                    DM, DM);
    castT(wk1, wqkv1t + (size_t)DM * DM,  DM, DM);
    castT(wv1, wqkv1t + 2ul * DM * DM,    DM, DM);
    castT(wq2, wq2t, DM, DM);
    castT(wk2, wkv2t,                   DM, DM);
    castT(wv2, wkv2t + (size_t)DM * DM, DM, DM);
    castT(wo1, wo1t, DM, DM);
    castT(wo2, wo2t, DM, DM);
    castT(wf1, wf1t, DM, DFFN);
    castT(wf2, wf2t, DFFN, DM);
    hipMemcpyAsync(bqkv1,          bq1, DM * 4, hipMemcpyDeviceToDevice, stream);
    hipMemcpyAsync(bqkv1 + DM,     bk1, DM * 4, hipMemcpyDeviceToDevice, stream);
    hipMemcpyAsync(bqkv1 + 2 * DM, bv1, DM * 4, hipMemcpyDeviceToDevice, stream);
    hipMemcpyAsync(bkv2,           bk2, DM * 4, hipMemcpyDeviceToDevice, stream);
    hipMemcpyAsync(bkv2 + DM,      bv2, DM * 4, hipMemcpyDeviceToDevice, stream);

    const int M = NB * SEQ;  // 4096
    dim3 gQKV(3 * DM / 128, M / 128);    // 768
    dim3 gKV(2 * DM / 128, M / 128);     // 512
    dim3 gDD64(DM / 128, M / 64);        // 512
    dim3 gDF(DFFN / 128, M / 128);       // 1024
    dim3 gAT(SEQ / 16, NB * NH);         // 4096

    // ---- MHA1 (self, causal) ----
    gemm_kernel<128, 128, 0, 1, 0, 1><<<gQKV, 256, 0, stream>>>(xb, wqkv1t, bqkv1, qkv1b, nullptr, v1t, 2048, M, 3 * DM, DM);
    attn_kernel<1><<<gAT, 256, 0, stream>>>(qkv1b, 3 * DM, qkv1b + DM, 3 * DM, v1t, nullptr, aw1, ctx);
    gemm_kernel<64, 128, 0, 0, 1, 0><<<gDD64, 256, 0, stream>>>(ctx, wo1t, bo1, nullptr, goutf, nullptr, 0, M, DM, DM);
    ln_kernel<1><<<M, 256, 0, stream>>>(goutf, x, g1, be1, out1f, out1b);

    // ---- MHA2 (cross, padding mask) ----
    gemm_kernel<64, 128, 0, 1, 0, 0><<<gDD64, 256, 0, stream>>>(out1b, wq2t, bq2, qb, nullptr, nullptr, 0, M, DM, DM);
    gemm_kernel<128, 128, 0, 1, 0, 1><<<gKV, 256, 0, stream>>>(encb, wkv2t, bkv2, kv2b, nullptr, v2t, 1024, M, 2 * DM, DM);
    attn_kernel<0><<<gAT, 256, 0, stream>>>(qb, DM, kv2b, 2 * DM, v2t, pad, aw2, ctx);
    gemm_kernel<64, 128, 0, 0, 1, 0><<<gDD64, 256, 0, stream>>>(ctx, wo2t, bo2, nullptr, goutf, nullptr, 0, M, DM, DM);
    ln_kernel<1><<<M, 256, 0, stream>>>(goutf, out1f, g2, be2, out2f, out2b);

    // ---- FFN ----
    gemm_kernel<128, 128, 1, 1, 0, 0><<<gDF, 256, 0, stream>>>(out2b, wf1t, bf1, ffn1b, nullptr, nullptr, 0, M, DFFN, DM);
    gemm_kernel<64, 128, 0, 0, 1, 0><<<gDD64, 256, 0, stream>>>(ffn1b, wf2t, bf2, nullptr, goutf, nullptr, 0, M, DM, DFFN);
    ln_kernel<0><<<M, 256, 0, stream>>>(goutf, out2f, g3, be3, out3, nullptr);
}

// Round 4
// 676.900 us; speedup vs baseline: 2.0541x; 1.4131x over previous
//
#include <hip/hip_runtime.h>

#define NB 4
#define SEQ 1024
#define DM 1024
#define NH 16
#define DEP 64
#define DFFN 4096

typedef __attribute__((ext_vector_type(8))) short short8;
typedef __attribute__((ext_vector_type(4))) float f32x4;
typedef __attribute__((ext_vector_type(4))) unsigned short us4;

__device__ __forceinline__ unsigned short f2bf(float f) {
    union { float f; unsigned int u; } v; v.f = f;
    unsigned int u = v.u;
    return (unsigned short)((u + 0x7FFFu + ((u >> 16) & 1u)) >> 16);
}

__device__ __forceinline__ void gload16(const void* g, void* l) {
    __builtin_amdgcn_global_load_lds((const __attribute__((address_space(1))) unsigned int*)g,
                                     (__attribute__((address_space(3))) unsigned int*)l, 16, 0, 0);
}

// ---------------- plain cast f32 -> bf16 ----------------
__global__ __launch_bounds__(256) void cast_bf16_kernel(const float* __restrict__ in,
                                                        unsigned short* __restrict__ out, int n4) {
    int i = blockIdx.x * 256 + threadIdx.x;
    if (i < n4) {
        float4 f = ((const float4*)in)[i];
        us4 u;
        u[0] = f2bf(f.x); u[1] = f2bf(f.y); u[2] = f2bf(f.z); u[3] = f2bf(f.w);
        ((us4*)out)[i] = u;
    }
}

// ---------------- transpose-cast: W (RxC f32) -> Wt (CxR bf16) ----------------
__global__ __launch_bounds__(256) void castT_kernel(const float* __restrict__ in,
                                                    unsigned short* __restrict__ out,
                                                    int R, int C) {
    __shared__ float tile[64][65];
    const int t = threadIdx.x;
    const int c0 = blockIdx.x * 64, r0 = blockIdx.y * 64;
#pragma unroll
    for (int p = 0; p < 4; ++p) {
        int r = p * 16 + (t >> 4), c = (t & 15) * 4;
        float4 f = *(const float4*)(in + (size_t)(r0 + r) * C + c0 + c);
        tile[r][c] = f.x; tile[r][c + 1] = f.y; tile[r][c + 2] = f.z; tile[r][c + 3] = f.w;
    }
    __syncthreads();
#pragma unroll
    for (int p = 0; p < 4; ++p) {
        int n = p * 16 + (t >> 4), k = (t & 15) * 4;
        us4 u;
#pragma unroll
        for (int j = 0; j < 4; ++j) u[j] = f2bf(tile[k + j][n]);
        *(us4*)(out + (size_t)(c0 + n) * R + r0 + k) = u;
    }
}

// ---------------- m97-style bf16 GEMM: C = A(MxK) @ Wt^T + bias ----------------
template <int BM, int BN, int RELU, int WB, int WF, int WVT>
__global__ __launch_bounds__(256) void gemm_kernel(const unsigned short* __restrict__ A,
                                                   const unsigned short* __restrict__ Wt,
                                                   const float* __restrict__ bias,
                                                   unsigned short* __restrict__ Cb,
                                                   float* __restrict__ Cf,
                                                   unsigned short* __restrict__ Vt,
                                                   int vstart,
                                                   int M, int N, int K) {
    constexpr int AM = BM / 32;
    constexpr int AI = BM / 64;
    constexpr int BI = BN / 64;
    __shared__ unsigned short As[BM * 32];
    __shared__ unsigned short Bs[BN * 32];
    const int t = threadIdx.x;
    const int lane = t & 63, w = t >> 6;
    const int m0 = blockIdx.y * BM, n0 = blockIdx.x * BN;
    const int wm = (w >> 1) * (BM / 2), wn = (w & 1) * (BN / 2);
    const int lr = lane & 15, g = lane >> 4, kb = g * 8;
    const int srow = lane >> 2, scol = (lane & 3) * 8;

    f32x4 acc[AM][4];
#pragma unroll
    for (int a = 0; a < AM; ++a)
#pragma unroll
        for (int b = 0; b < 4; ++b)
#pragma unroll
            for (int j = 0; j < 4; ++j) acc[a][b][j] = 0.f;

    for (int kt = 0; kt < K; kt += 32) {
        __syncthreads();
#pragma unroll
        for (int ia = 0; ia < AI; ++ia) {
            int rb = w * (BM / 4) + ia * 16;
            gload16(A + (size_t)(m0 + rb + srow) * K + kt + scol, As + rb * 32);
        }
#pragma unroll
        for (int ib = 0; ib < BI; ++ib) {
            int rb = w * (BN / 4) + ib * 16;
            gload16(Wt + (size_t)(n0 + rb + srow) * K + kt + scol, Bs + rb * 32);
        }
        __syncthreads();

        short8 af[AM], bfr[4];
#pragma unroll
        for (int i = 0; i < AM; ++i) af[i] = *(const short8*)&As[(wm + i * 16 + lr) * 32 + kb];
#pragma unroll
        for (int i = 0; i < 4; ++i) bfr[i] = *(const short8*)&Bs[(wn + i * 16 + lr) * 32 + kb];
#pragma unroll
        for (int am = 0; am < AM; ++am)
#pragma unroll
            for (int bn = 0; bn < 4; ++bn)
                acc[am][bn] = __builtin_amdgcn_mfma_f32_16x16x32_bf16(af[am], bfr[bn], acc[am][bn], 0, 0, 0);
    }

#pragma unroll
    for (int am = 0; am < AM; ++am) {
#pragma unroll
        for (int bn = 0; bn < 4; ++bn) {
            int col = n0 + wn + bn * 16 + lr;
            float bv = bias ? bias[col] : 0.f;
            int rowb = m0 + wm + am * 16 + g * 4;
            float vv[4];
#pragma unroll
            for (int i = 0; i < 4; ++i) {
                float v = acc[am][bn][i] + bv;
                if (RELU) v = v > 0.f ? v : 0.f;
                vv[i] = v;
                if (WF) Cf[(size_t)(rowb + i) * N + col] = v;
                if (WB) Cb[(size_t)(rowb + i) * N + col] = f2bf(v);
            }
            if (WVT && col >= vstart) {
                int h = (col - vstart) >> 6, dep = (col - vstart) & 63;
                int b = rowb >> 10, kpos = rowb & 1023;
                us4 u;
#pragma unroll
                for (int i = 0; i < 4; ++i) u[i] = f2bf(vv[i]);
                *(us4*)(Vt + ((size_t)(b * NH + h) * DEP + dep) * SEQ + kpos) = u;
            }
        }
    }
}

// ---------------- fused attention v2: swapped QK^T + softmax + aw(float4) + PV ----------------
// 1D grid 4096; id decode puts all 64 q-tiles of a head on one XCD.
// Lane holds S^T: q = q0 + (lane&15) fixed, k = kc*256 + w*64 + bn*16 + g*4 + i.
template <int CAUSAL>
__global__ __launch_bounds__(256) void attn_kernel(const unsigned short* __restrict__ Q, int ldq,
                                                   const unsigned short* __restrict__ Kp, int ldk,
                                                   const unsigned short* __restrict__ Vt,
                                                   const float* __restrict__ pad,
                                                   float* __restrict__ aw,
                                                   unsigned short* __restrict__ ctx) {
    __shared__ unsigned short Ks[256][72];
    __shared__ unsigned short Pch[16 * 256];  // stride 512 B, XOR-swizzled
    __shared__ float redm[4][16];
    __shared__ float reds[4][16];
    const int t = threadIdx.x, lane = t & 63, w = t >> 6;
    const int lr = lane & 15, g = lane >> 4;
    const int id = blockIdx.x;
    const int bh = (id & 7) + ((id >> 9) << 3);   // xcd = bh % 8
    const int qt = (id >> 3) & 63;
    const int q0 = qt * 16;
    const int b = bh >> 4, h = bh & 15;
    const int q = q0 + lr;
    const size_t qbase = (size_t)b * SEQ * ldq + (size_t)h * DEP;
    const size_t kbase = (size_t)b * SEQ * ldk + (size_t)h * DEP;
    const int kcmax = CAUSAL ? (q0 >> 8) + 1 : 4;

    short8 aq[2];
#pragma unroll
    for (int ks = 0; ks < 2; ++ks)
        aq[ks] = *(const short8*)(Q + qbase + (size_t)q * ldq + ks * 32 + g * 8);

    f32x4 acc[4][4];
#pragma unroll
    for (int a = 0; a < 4; ++a)
#pragma unroll
        for (int b2 = 0; b2 < 4; ++b2)
#pragma unroll
            for (int j = 0; j < 4; ++j) acc[a][b2][j] = 0.f;

    // ---- QK^T (swapped: mfma(K,Q) -> S^T) ----
#pragma unroll
    for (int kc = 0; kc < 4; ++kc) {
        if (kc < kcmax) {
            __syncthreads();
#pragma unroll
            for (int p = 0; p < 8; ++p) {
                int idx = p * 256 + t;
                int r = idx >> 3, c8 = (idx & 7) * 8;
                *(short8*)&Ks[r][c8] = *(const short8*)(Kp + kbase + (size_t)(kc * 256 + r) * ldk + c8);
            }
            __syncthreads();
#pragma unroll
            for (int ks = 0; ks < 2; ++ks)
#pragma unroll
                for (int bn = 0; bn < 4; ++bn) {
                    short8 bk = *(const short8*)&Ks[w * 64 + bn * 16 + lr][ks * 32 + g * 8];
                    acc[kc][bn] = __builtin_amdgcn_mfma_f32_16x16x32_bf16(bk, aq[ks], acc[kc][bn], 0, 0, 0);
                }
        }
    }

    // ---- scale + masks + row max ----
    float mrow = -1e30f;
#pragma unroll
    for (int kc = 0; kc < 4; ++kc) {
        if (kc < kcmax) {
#pragma unroll
            for (int bn = 0; bn < 4; ++bn) {
                int k4 = kc * 256 + w * 64 + bn * 16 + g * 4;
                f32x4 pv = {0.f, 0.f, 0.f, 0.f};
                if (pad) pv = *(const f32x4*)(pad + (size_t)b * SEQ + k4);
#pragma unroll
                for (int i = 0; i < 4; ++i) {
                    float v = acc[kc][bn][i] * 0.125f + pv[i] * -1e9f;
                    if (CAUSAL && (k4 + i) > q) v = -1e30f;
                    acc[kc][bn][i] = v;
                    mrow = fmaxf(mrow, v);
                }
            }
        }
    }
    mrow = fmaxf(mrow, __shfl_xor(mrow, 16));
    mrow = fmaxf(mrow, __shfl_xor(mrow, 32));
    if (lane < 16) redm[w][lr] = mrow;
    __syncthreads();
    const float M = fmaxf(fmaxf(redm[0][lr], redm[1][lr]), fmaxf(redm[2][lr], redm[3][lr]));

    // ---- exp + row sum ----
    float srow = 0.f;
#pragma unroll
    for (int kc = 0; kc < 4; ++kc) {
        if (kc < kcmax) {
#pragma unroll
            for (int bn = 0; bn < 4; ++bn)
#pragma unroll
                for (int i = 0; i < 4; ++i) {
                    float e = __expf(acc[kc][bn][i] - M);
                    acc[kc][bn][i] = e;
                    srow += e;
                }
        }
    }
    srow += __shfl_xor(srow, 16);
    srow += __shfl_xor(srow, 32);
    if (lane < 16) reds[w][lr] = srow;
    __syncthreads();
    const float inv = 1.0f / (reds[0][lr] + reds[1][lr] + reds[2][lr] + reds[3][lr]);

    // ---- aw writes: float4 per (kc,bn), zero-fill beyond kcmax ----
    float* awrow = aw + ((size_t)bh * SEQ + q) * SEQ;
#pragma unroll
    for (int kc = 0; kc < 4; ++kc)
#pragma unroll
        for (int bn = 0; bn < 4; ++bn) {
            f32x4 o = {0.f, 0.f, 0.f, 0.f};
            if (kc < kcmax) {
#pragma unroll
                for (int i = 0; i < 4; ++i) o[i] = acc[kc][bn][i] * inv;
            }
            *(f32x4*)(awrow + kc * 256 + w * 64 + bn * 16 + g * 4) = o;
        }

    // ---- PV: per-kc P-chunk in swizzled LDS; wave w owns d-tile w*16 ----
    f32x4 acc2;
#pragma unroll
    for (int j = 0; j < 4; ++j) acc2[j] = 0.f;
    char* pch = (char*)Pch;
    const int sw = (lr & 7) << 4;
#pragma unroll
    for (int kc = 0; kc < 4; ++kc) {
        if (kc < kcmax) {
            __syncthreads();
#pragma unroll
            for (int bn = 0; bn < 4; ++bn) {
                us4 u;
#pragma unroll
                for (int i = 0; i < 4; ++i) u[i] = f2bf(acc[kc][bn][i] * inv);
                *(us4*)(pch + lr * 512 + ((w * 128 + bn * 32 + g * 8) ^ sw)) = u;
            }
            __syncthreads();
#pragma unroll
            for (int ks = 0; ks < 8; ++ks) {
                short8 af = *(const short8*)(pch + lr * 512 + ((ks * 64 + g * 16) ^ sw));
                short8 bf = *(const short8*)(Vt + ((size_t)bh * DEP + w * 16 + lr) * SEQ + kc * 256 + ks * 32 + g * 8);
                acc2 = __builtin_amdgcn_mfma_f32_16x16x32_bf16(af, bf, acc2, 0, 0, 0);
            }
        }
    }
#pragma unroll
    for (int i = 0; i < 4; ++i)
        ctx[((size_t)b * SEQ + q0 + g * 4 + i) * DM + h * DEP + w * 16 + lr] = f2bf(acc2[i]);
}

// ---------------- residual + layernorm ----------------
template <int WB>
__global__ __launch_bounds__(256) void ln_kernel(const float* __restrict__ X,
                                                 const float* __restrict__ R,
                                                 const float* __restrict__ gamma,
                                                 const float* __restrict__ beta,
                                                 float* __restrict__ outF,
                                                 unsigned short* __restrict__ outB) {
    size_t row = blockIdx.x;
    const int t = threadIdx.x;
    float4 a = ((const float4*)(X + (row << 10)))[t];
    float4 r = ((const float4*)(R + (row << 10)))[t];
    float v0 = a.x + r.x, v1 = a.y + r.y, v2 = a.z + r.z, v3 = a.w + r.w;
    float s = v0 + v1 + v2 + v3;
    float q = v0 * v0 + v1 * v1 + v2 * v2 + v3 * v3;
#pragma unroll
    for (int off = 32; off; off >>= 1) {
        s += __shfl_down(s, off);
        q += __shfl_down(q, off);
    }
    __shared__ float rs[4], rq[4];
    if ((t & 63) == 0) { rs[t >> 6] = s; rq[t >> 6] = q; }
    __syncthreads();
    s = rs[0] + rs[1] + rs[2] + rs[3];
    q = rq[0] + rq[1] + rq[2] + rq[3];
    float mean = s * (1.0f / 1024.0f);
    float var = q * (1.0f / 1024.0f) - mean * mean;
    float inv = rsqrtf(var + 1e-6f);
    float g0 = gamma[t * 4], g1 = gamma[t * 4 + 1], g2 = gamma[t * 4 + 2], g3 = gamma[t * 4 + 3];
    float b0 = beta[t * 4], b1 = beta[t * 4 + 1], b2 = beta[t * 4 + 2], b3 = beta[t * 4 + 3];
    float o0 = (v0 - mean) * inv * g0 + b0;
    float o1 = (v1 - mean) * inv * g1 + b1;
    float o2 = (v2 - mean) * inv * g2 + b2;
    float o3 = (v3 - mean) * inv * g3 + b3;
    float4 o; o.x = o0; o.y = o1; o.z = o2; o.w = o3;
    ((float4*)(outF + (row << 10)))[t] = o;
    if (WB) {
        us4 u;
        u[0] = f2bf(o0); u[1] = f2bf(o1); u[2] = f2bf(o2); u[3] = f2bf(o3);
        ((us4*)(outB + (row << 10)))[t] = u;
    }
}

extern "C" void kernel_launch(void* const* d_in, const int* in_sizes, int n_in,
                              void* d_out, int out_size, void* d_ws, size_t ws_size,
                              hipStream_t stream) {
    const float* x = (const float*)d_in[0];
    const float* enc = (const float*)d_in[1];
    const float* pad = (const float*)d_in[3];
    const float* wq1 = (const float*)d_in[4];  const float* bq1 = (const float*)d_in[5];
    const float* wk1 = (const float*)d_in[6];  const float* bk1 = (const float*)d_in[7];
    const float* wv1 = (const float*)d_in[8];  const float* bv1 = (const float*)d_in[9];
    const float* wo1 = (const float*)d_in[10]; const float* bo1 = (const float*)d_in[11];
    const float* wq2 = (const float*)d_in[12]; const float* bq2 = (const float*)d_in[13];
    const float* wk2 = (const float*)d_in[14]; const float* bk2 = (const float*)d_in[15];
    const float* wv2 = (const float*)d_in[16]; const float* bv2 = (const float*)d_in[17];
    const float* wo2 = (const float*)d_in[18]; const float* bo2 = (const float*)d_in[19];
    const float* wf1 = (const float*)d_in[20]; const float* bf1 = (const float*)d_in[21];
    const float* wf2 = (const float*)d_in[22]; const float* bf2 = (const float*)d_in[23];
    const float* g1 = (const float*)d_in[24]; const float* be1 = (const float*)d_in[25];
    const float* g2 = (const float*)d_in[26]; const float* be2 = (const float*)d_in[27];
    const float* g3 = (const float*)d_in[28]; const float* be3 = (const float*)d_in[29];

    float* out3 = (float*)d_out;
    float* aw1 = out3 + (size_t)NB * SEQ * DM;
    float* aw2 = aw1 + (size_t)NB * NH * SEQ * SEQ;

    char* ws = (char*)d_ws;
    size_t off = 0;
    auto take = [&](size_t n) { char* p = ws + off; off += (n + 255) & ~(size_t)255; return p; };
    const size_t SZ_SD_BF = (size_t)NB * SEQ * DM * 2;
    const size_t SZ_SD_F  = (size_t)NB * SEQ * DM * 4;
    const size_t SZ_DD_BF = (size_t)DM * DM * 2;

    unsigned short* wqkv1t = (unsigned short*)take(3 * SZ_DD_BF);
    unsigned short* wq2t   = (unsigned short*)take(SZ_DD_BF);
    unsigned short* wkv2t  = (unsigned short*)take(2 * SZ_DD_BF);
    unsigned short* wo1t   = (unsigned short*)take(SZ_DD_BF);
    unsigned short* wo2t   = (unsigned short*)take(SZ_DD_BF);
    unsigned short* wf1t   = (unsigned short*)take((size_t)DM * DFFN * 2);
    unsigned short* wf2t   = (unsigned short*)take((size_t)DFFN * DM * 2);
    float* bqkv1 = (float*)take(3 * DM * 4);
    float* bkv2  = (float*)take(2 * DM * 4);
    unsigned short* xb    = (unsigned short*)take(SZ_SD_BF);
    unsigned short* encb  = (unsigned short*)take(SZ_SD_BF);
    unsigned short* qkv1b = (unsigned short*)take(3 * SZ_SD_BF);
    unsigned short* v1t   = (unsigned short*)take(SZ_SD_BF);
    unsigned short* qb    = (unsigned short*)take(SZ_SD_BF);
    unsigned short* kv2b  = (unsigned short*)take(2 * SZ_SD_BF);
    unsigned short* v2t   = (unsigned short*)take(SZ_SD_BF);
    unsigned short* ctx   = (unsigned short*)take(SZ_SD_BF);
    float* goutf = (float*)take(SZ_SD_F);
    float* out1f = (float*)take(SZ_SD_F);
    unsigned short* out1b = (unsigned short*)take(SZ_SD_BF);
    float* out2f = (float*)take(SZ_SD_F);
    unsigned short* out2b = (unsigned short*)take(SZ_SD_BF);
    unsigned short* ffn1b = (unsigned short*)take((size_t)NB * SEQ * DFFN * 2);

    auto cast = [&](const float* src, unsigned short* dst, size_t n) {
        cast_bf16_kernel<<<(unsigned)((n / 4 + 255) / 256), 256, 0, stream>>>(src, dst, (int)(n / 4));
    };
    auto castT = [&](const float* src, unsigned short* dst, int R, int C) {
        dim3 gr(C / 64, R / 64);
        castT_kernel<<<gr, 256, 0, stream>>>(src, dst, R, C);
    };
    cast(x, xb, (size_t)NB * SEQ * DM);
    cast(enc, encb, (size_t)NB * SEQ * DM);
    castT(wq1, wqkv1t,                    DM, DM);
    castT(wk1, wqkv1t + (size_t)DM * DM,  DM, DM);
    castT(wv1, wqkv1t + 2ul * DM * DM,    DM, DM);
    castT(wq2, wq2t, DM, DM);
    castT(wk2, wkv2t,                   DM, DM);
    castT(wv2, wkv2t + (size_t)DM * DM, DM, DM);
    castT(wo1, wo1t, DM, DM);
    castT(wo2, wo2t, DM, DM);
    castT(wf1, wf1t, DM, DFFN);
    castT(wf2, wf2t, DFFN, DM);
    hipMemcpyAsync(bqkv1,          bq1, DM * 4, hipMemcpyDeviceToDevice, stream);
    hipMemcpyAsync(bqkv1 + DM,     bk1, DM * 4, hipMemcpyDeviceToDevice, stream);
    hipMemcpyAsync(bqkv1 + 2 * DM, bv1, DM * 4, hipMemcpyDeviceToDevice, stream);
    hipMemcpyAsync(bkv2,           bk2, DM * 4, hipMemcpyDeviceToDevice, stream);
    hipMemcpyAsync(bkv2 + DM,      bv2, DM * 4, hipMemcpyDeviceToDevice, stream);

    const int M = NB * SEQ;
    dim3 gQKV(3 * DM / 128, M / 128);
    dim3 gKV(2 * DM / 128, M / 128);
    dim3 gDD64(DM / 128, M / 64);
    dim3 gDF(DFFN / 128, M / 128);

    // ---- MHA1 (self, causal) ----
    gemm_kernel<128, 128, 0, 1, 0, 1><<<gQKV, 256, 0, stream>>>(xb, wqkv1t, bqkv1, qkv1b, nullptr, v1t, 2048, M, 3 * DM, DM);
    attn_kernel<1><<<4096, 256, 0, stream>>>(qkv1b, 3 * DM, qkv1b + DM, 3 * DM, v1t, nullptr, aw1, ctx);
    gemm_kernel<64, 128, 0, 0, 1, 0><<<gDD64, 256, 0, stream>>>(ctx, wo1t, bo1, nullptr, goutf, nullptr, 0, M, DM, DM);
    ln_kernel<1><<<M, 256, 0, stream>>>(goutf, x, g1, be1, out1f, out1b);

    // ---- MHA2 (cross, padding mask) ----
    gemm_kernel<64, 128, 0, 1, 0, 0><<<gDD64, 256, 0, stream>>>(out1b, wq2t, bq2, qb, nullptr, nullptr, 0, M, DM, DM);
    gemm_kernel<128, 128, 0, 1, 0, 1><<<gKV, 256, 0, stream>>>(encb, wkv2t, bkv2, kv2b, nullptr, v2t, 1024, M, 2 * DM, DM);
    attn_kernel<0><<<4096, 256, 0, stream>>>(qb, DM, kv2b, 2 * DM, v2t, pad, aw2, ctx);
    gemm_kernel<64, 128, 0, 0, 1, 0><<<gDD64, 256, 0, stream>>>(ctx, wo2t, bo2, nullptr, goutf, nullptr, 0, M, DM, DM);
    ln_kernel<1><<<M, 256, 0, stream>>>(goutf, out1f, g2, be2, out2f, out2b);

    // ---- FFN ----
    gemm_kernel<128, 128, 1, 1, 0, 0><<<gDF, 256, 0, stream>>>(out2b, wf1t, bf1, ffn1b, nullptr, nullptr, 0, M, DFFN, DM);
    gemm_kernel<64, 128, 0, 0, 1, 0><<<gDD64, 256, 0, stream>>>(ffn1b, wf2t, bf2, nullptr, goutf, nullptr, 0, M, DM, DFFN);
    ln_kernel<0><<<M, 256, 0, stream>>>(goutf, out2f, g3, be3, out3, nullptr);
}

// Round 5
// 642.404 us; speedup vs baseline: 2.1644x; 1.0537x over previous
//
#include <hip/hip_runtime.h>

#define NB 4
#define SEQ 1024
#define DM 1024
#define NH 16
#define DEP 64
#define DFFN 4096

typedef __attribute__((ext_vector_type(8))) short short8;
typedef __attribute__((ext_vector_type(4))) float f32x4;
typedef __attribute__((ext_vector_type(4))) unsigned short us4;

__device__ __forceinline__ unsigned short f2bf(float f) {
    union { float f; unsigned int u; } v; v.f = f;
    unsigned int u = v.u;
    return (unsigned short)((u + 0x7FFFu + ((u >> 16) & 1u)) >> 16);
}

__device__ __forceinline__ void gload16(const void* g, void* l) {
    __builtin_amdgcn_global_load_lds((const __attribute__((address_space(1))) unsigned int*)g,
                                     (__attribute__((address_space(3))) unsigned int*)l, 16, 0, 0);
}

// ---------------- dual cast f32 -> bf16 (x and enc in one launch) ----------------
__global__ __launch_bounds__(256) void cast2_kernel(const float* __restrict__ a,
                                                    const float* __restrict__ b,
                                                    unsigned short* __restrict__ oa,
                                                    unsigned short* __restrict__ ob, int n4) {
    int i = blockIdx.x * 256 + threadIdx.x;
    const float* in = blockIdx.y ? b : a;
    unsigned short* out = blockIdx.y ? ob : oa;
    if (i < n4) {
        float4 f = ((const float4*)in)[i];
        us4 u;
        u[0] = f2bf(f.x); u[1] = f2bf(f.y); u[2] = f2bf(f.z); u[3] = f2bf(f.w);
        ((us4*)out)[i] = u;
    }
}

// ---------------- transpose-cast: W (RxC f32) -> Wt (CxR bf16) ----------------
__global__ __launch_bounds__(256) void castT_kernel(const float* __restrict__ in,
                                                    unsigned short* __restrict__ out,
                                                    int R, int C) {
    __shared__ float tile[64][65];
    const int t = threadIdx.x;
    const int c0 = blockIdx.x * 64, r0 = blockIdx.y * 64;
#pragma unroll
    for (int p = 0; p < 4; ++p) {
        int r = p * 16 + (t >> 4), c = (t & 15) * 4;
        float4 f = *(const float4*)(in + (size_t)(r0 + r) * C + c0 + c);
        tile[r][c] = f.x; tile[r][c + 1] = f.y; tile[r][c + 2] = f.z; tile[r][c + 3] = f.w;
    }
    __syncthreads();
#pragma unroll
    for (int p = 0; p < 4; ++p) {
        int n = p * 16 + (t >> 4), k = (t & 15) * 4;
        us4 u;
#pragma unroll
        for (int j = 0; j < 4; ++j) u[j] = f2bf(tile[k + j][n]);
        *(us4*)(out + (size_t)(c0 + n) * R + r0 + k) = u;
    }
}

// ---------------- batched transpose-cast for 8 DMxDM weights ----------------
struct P8 { const float* p[8]; };
__global__ __launch_bounds__(256) void castT8_kernel(P8 srcs, unsigned short* __restrict__ dstbase) {
    __shared__ float tile[64][65];
    const float* in = srcs.p[blockIdx.z];
    unsigned short* out = dstbase + (size_t)blockIdx.z * DM * DM;
    const int t = threadIdx.x;
    const int c0 = blockIdx.x * 64, r0 = blockIdx.y * 64;
#pragma unroll
    for (int p = 0; p < 4; ++p) {
        int r = p * 16 + (t >> 4), c = (t & 15) * 4;
        float4 f = *(const float4*)(in + (size_t)(r0 + r) * DM + c0 + c);
        tile[r][c] = f.x; tile[r][c + 1] = f.y; tile[r][c + 2] = f.z; tile[r][c + 3] = f.w;
    }
    __syncthreads();
#pragma unroll
    for (int p = 0; p < 4; ++p) {
        int n = p * 16 + (t >> 4), k = (t & 15) * 4;
        us4 u;
#pragma unroll
        for (int j = 0; j < 4; ++j) u[j] = f2bf(tile[k + j][n]);
        *(us4*)(out + (size_t)(c0 + n) * DM + r0 + k) = u;
    }
}

// ---------------- bias concat pack (replaces 5 memcpys) ----------------
__global__ __launch_bounds__(256) void biaspack_kernel(const float* __restrict__ bq1,
                                                       const float* __restrict__ bk1,
                                                       const float* __restrict__ bv1,
                                                       const float* __restrict__ bk2,
                                                       const float* __restrict__ bv2,
                                                       float* __restrict__ bqkv1,
                                                       float* __restrict__ bkv2) {
    int i = blockIdx.x * 256 + threadIdx.x;
    if (i < 1024) bqkv1[i] = bq1[i];
    else if (i < 2048) bqkv1[i] = bk1[i - 1024];
    else if (i < 3072) bqkv1[i] = bv1[i - 2048];
    else if (i < 4096) bkv2[i - 3072] = bk2[i - 3072];
    else if (i < 5120) bkv2[i - 3072] = bv2[i - 4096];
}

// ---------------- m97-style bf16 GEMM: C = A(MxK) @ Wt^T + bias ----------------
// Wt row-major [N][K]. KSPLIT=2: blockIdx.z picks K-half; z=0 -> Cf (+bias), z=1 -> Cf2.
template <int BM, int BN, int BK, int KSPLIT, int RELU, int WB, int WF, int WVT>
__global__ __launch_bounds__(256) void gemm_kernel(const unsigned short* __restrict__ A,
                                                   const unsigned short* __restrict__ Wt,
                                                   const float* __restrict__ bias,
                                                   unsigned short* __restrict__ Cb,
                                                   float* __restrict__ Cf,
                                                   float* __restrict__ Cf2,
                                                   unsigned short* __restrict__ Vt,
                                                   int vstart,
                                                   int M, int N, int K) {
    constexpr int AM = BM / 32;
    constexpr int KS = BK / 32;
    constexpr int LPR = BK / 8;          // lanes per LDS row-segment
    constexpr int RPI = 64 / LPR;        // rows per gload issue
    constexpr int AR = (BM / 4) / RPI;   // A issues per wave
    constexpr int BR = (BN / 4) / RPI;
    __shared__ unsigned short As[BM * BK];
    __shared__ unsigned short Bs[BN * BK];
    const int t = threadIdx.x;
    const int lane = t & 63, w = t >> 6;
    const int m0 = blockIdx.y * BM, n0 = blockIdx.x * BN;
    const int wm = (w >> 1) * (BM / 2), wn = (w & 1) * (BN / 2);
    const int lr = lane & 15, g = lane >> 4, kb = g * 8;
    const int srow = lane / LPR, scol = (lane % LPR) * 8;
    const int kofs = (KSPLIT == 2 && blockIdx.z) ? K / 2 : 0;
    const int Keff = (KSPLIT == 2) ? K / 2 : K;

    f32x4 acc[AM][4];
#pragma unroll
    for (int a = 0; a < AM; ++a)
#pragma unroll
        for (int b = 0; b < 4; ++b)
#pragma unroll
            for (int j = 0; j < 4; ++j) acc[a][b][j] = 0.f;

    for (int kt = 0; kt < Keff; kt += BK) {
        __syncthreads();
#pragma unroll
        for (int ia = 0; ia < AR; ++ia) {
            int rb = w * (BM / 4) + ia * RPI;
            gload16(A + (size_t)(m0 + rb + srow) * K + kofs + kt + scol, As + rb * BK);
        }
#pragma unroll
        for (int ib = 0; ib < BR; ++ib) {
            int rb = w * (BN / 4) + ib * RPI;
            gload16(Wt + (size_t)(n0 + rb + srow) * K + kofs + kt + scol, Bs + rb * BK);
        }
        __syncthreads();

        short8 af[AM][KS], bfr[4][KS];
#pragma unroll
        for (int i = 0; i < AM; ++i)
#pragma unroll
            for (int ks = 0; ks < KS; ++ks)
                af[i][ks] = *(const short8*)&As[(wm + i * 16 + lr) * BK + ks * 32 + kb];
#pragma unroll
        for (int i = 0; i < 4; ++i)
#pragma unroll
            for (int ks = 0; ks < KS; ++ks)
                bfr[i][ks] = *(const short8*)&Bs[(wn + i * 16 + lr) * BK + ks * 32 + kb];
#pragma unroll
        for (int ks = 0; ks < KS; ++ks)
#pragma unroll
            for (int am = 0; am < AM; ++am)
#pragma unroll
                for (int bn = 0; bn < 4; ++bn)
                    acc[am][bn] = __builtin_amdgcn_mfma_f32_16x16x32_bf16(af[am][ks], bfr[bn][ks], acc[am][bn], 0, 0, 0);
    }

    float* cfo = (KSPLIT == 2 && blockIdx.z) ? Cf2 : Cf;
    const bool addb = bias && (KSPLIT == 1 || blockIdx.z == 0);
#pragma unroll
    for (int am = 0; am < AM; ++am) {
#pragma unroll
        for (int bn = 0; bn < 4; ++bn) {
            int col = n0 + wn + bn * 16 + lr;
            float bv = addb ? bias[col] : 0.f;
            int rowb = m0 + wm + am * 16 + g * 4;
            float vv[4];
#pragma unroll
            for (int i = 0; i < 4; ++i) {
                float v = acc[am][bn][i] + bv;
                if (RELU) v = v > 0.f ? v : 0.f;
                vv[i] = v;
                if (WF) cfo[(size_t)(rowb + i) * N + col] = v;
                if (WB) Cb[(size_t)(rowb + i) * N + col] = f2bf(v);
            }
            if (WVT && col >= vstart) {
                int h = (col - vstart) >> 6, dep = (col - vstart) & 63;
                int b = rowb >> 10, kpos = rowb & 1023;
                us4 u;
#pragma unroll
                for (int i = 0; i < 4; ++i) u[i] = f2bf(vv[i]);
                *(us4*)(Vt + ((size_t)(b * NH + h) * DEP + dep) * SEQ + kpos) = u;
            }
        }
    }
}

// ---------------- fused attention: swapped QK^T + softmax + aw(float4) + PV ----------------
template <int CAUSAL>
__global__ __launch_bounds__(256) void attn_kernel(const unsigned short* __restrict__ Q, int ldq,
                                                   const unsigned short* __restrict__ Kp, int ldk,
                                                   const unsigned short* __restrict__ Vt,
                                                   const float* __restrict__ pad,
                                                   float* __restrict__ aw,
                                                   unsigned short* __restrict__ ctx) {
    __shared__ unsigned short Ks[256][72];
    __shared__ unsigned short Pch[16 * 256];
    __shared__ float redm[4][16];
    __shared__ float reds[4][16];
    const int t = threadIdx.x, lane = t & 63, w = t >> 6;
    const int lr = lane & 15, g = lane >> 4;
    const int id = blockIdx.x;
    const int bh = (id & 7) + ((id >> 9) << 3);
    const int qt = (id >> 3) & 63;
    const int q0 = qt * 16;
    const int b = bh >> 4, h = bh & 15;
    const int q = q0 + lr;
    const size_t qbase = (size_t)b * SEQ * ldq + (size_t)h * DEP;
    const size_t kbase = (size_t)b * SEQ * ldk + (size_t)h * DEP;
    const int kcmax = CAUSAL ? (q0 >> 8) + 1 : 4;

    short8 aq[2];
#pragma unroll
    for (int ks = 0; ks < 2; ++ks)
        aq[ks] = *(const short8*)(Q + qbase + (size_t)q * ldq + ks * 32 + g * 8);

    f32x4 acc[4][4];
#pragma unroll
    for (int a = 0; a < 4; ++a)
#pragma unroll
        for (int b2 = 0; b2 < 4; ++b2)
#pragma unroll
            for (int j = 0; j < 4; ++j) acc[a][b2][j] = 0.f;

#pragma unroll
    for (int kc = 0; kc < 4; ++kc) {
        if (kc < kcmax) {
            __syncthreads();
#pragma unroll
            for (int p = 0; p < 8; ++p) {
                int idx = p * 256 + t;
                int r = idx >> 3, c8 = (idx & 7) * 8;
                *(short8*)&Ks[r][c8] = *(const short8*)(Kp + kbase + (size_t)(kc * 256 + r) * ldk + c8);
            }
            __syncthreads();
#pragma unroll
            for (int ks = 0; ks < 2; ++ks)
#pragma unroll
                for (int bn = 0; bn < 4; ++bn) {
                    short8 bk = *(const short8*)&Ks[w * 64 + bn * 16 + lr][ks * 32 + g * 8];
                    acc[kc][bn] = __builtin_amdgcn_mfma_f32_16x16x32_bf16(bk, aq[ks], acc[kc][bn], 0, 0, 0);
                }
        }
    }

    float mrow = -1e30f;
#pragma unroll
    for (int kc = 0; kc < 4; ++kc) {
        if (kc < kcmax) {
#pragma unroll
            for (int bn = 0; bn < 4; ++bn) {
                int k4 = kc * 256 + w * 64 + bn * 16 + g * 4;
                f32x4 pv = {0.f, 0.f, 0.f, 0.f};
                if (pad) pv = *(const f32x4*)(pad + (size_t)b * SEQ + k4);
#pragma unroll
                for (int i = 0; i < 4; ++i) {
                    float v = acc[kc][bn][i] * 0.125f + pv[i] * -1e9f;
                    if (CAUSAL && (k4 + i) > q) v = -1e30f;
                    acc[kc][bn][i] = v;
                    mrow = fmaxf(mrow, v);
                }
            }
        }
    }
    mrow = fmaxf(mrow, __shfl_xor(mrow, 16));
    mrow = fmaxf(mrow, __shfl_xor(mrow, 32));
    if (lane < 16) redm[w][lr] = mrow;
    __syncthreads();
    const float M = fmaxf(fmaxf(redm[0][lr], redm[1][lr]), fmaxf(redm[2][lr], redm[3][lr]));

    float srow = 0.f;
#pragma unroll
    for (int kc = 0; kc < 4; ++kc) {
        if (kc < kcmax) {
#pragma unroll
            for (int bn = 0; bn < 4; ++bn)
#pragma unroll
                for (int i = 0; i < 4; ++i) {
                    float e = __expf(acc[kc][bn][i] - M);
                    acc[kc][bn][i] = e;
                    srow += e;
                }
        }
    }
    srow += __shfl_xor(srow, 16);
    srow += __shfl_xor(srow, 32);
    if (lane < 16) reds[w][lr] = srow;
    __syncthreads();
    const float inv = 1.0f / (reds[0][lr] + reds[1][lr] + reds[2][lr] + reds[3][lr]);

    float* awrow = aw + ((size_t)bh * SEQ + q) * SEQ;
#pragma unroll
    for (int kc = 0; kc < 4; ++kc)
#pragma unroll
        for (int bn = 0; bn < 4; ++bn) {
            f32x4 o = {0.f, 0.f, 0.f, 0.f};
            if (kc < kcmax) {
#pragma unroll
                for (int i = 0; i < 4; ++i) o[i] = acc[kc][bn][i] * inv;
            }
            *(f32x4*)(awrow + kc * 256 + w * 64 + bn * 16 + g * 4) = o;
        }

    f32x4 acc2;
#pragma unroll
    for (int j = 0; j < 4; ++j) acc2[j] = 0.f;
    char* pch = (char*)Pch;
    const int sw = (lr & 7) << 4;
#pragma unroll
    for (int kc = 0; kc < 4; ++kc) {
        if (kc < kcmax) {
            __syncthreads();
#pragma unroll
            for (int bn = 0; bn < 4; ++bn) {
                us4 u;
#pragma unroll
                for (int i = 0; i < 4; ++i) u[i] = f2bf(acc[kc][bn][i] * inv);
                *(us4*)(pch + lr * 512 + ((w * 128 + bn * 32 + g * 8) ^ sw)) = u;
            }
            __syncthreads();
#pragma unroll
            for (int ks = 0; ks < 8; ++ks) {
                short8 af = *(const short8*)(pch + lr * 512 + ((ks * 64 + g * 16) ^ sw));
                short8 bf = *(const short8*)(Vt + ((size_t)bh * DEP + w * 16 + lr) * SEQ + kc * 256 + ks * 32 + g * 8);
                acc2 = __builtin_amdgcn_mfma_f32_16x16x32_bf16(af, bf, acc2, 0, 0, 0);
            }
        }
    }
#pragma unroll
    for (int i = 0; i < 4; ++i)
        ctx[((size_t)b * SEQ + q0 + g * 4 + i) * DM + h * DEP + w * 16 + lr] = f2bf(acc2[i]);
}

// ---------------- residual + layernorm: out = LN(X [+ X2] + R) ----------------
template <int WB, int X2EN>
__global__ __launch_bounds__(256) void ln_kernel(const float* __restrict__ X,
                                                 const float* __restrict__ X2,
                                                 const float* __restrict__ R,
                                                 const float* __restrict__ gamma,
                                                 const float* __restrict__ beta,
                                                 float* __restrict__ outF,
                                                 unsigned short* __restrict__ outB) {
    size_t row = blockIdx.x;
    const int t = threadIdx.x;
    float4 a = ((const float4*)(X + (row << 10)))[t];
    float4 r = ((const float4*)(R + (row << 10)))[t];
    float v0 = a.x + r.x, v1 = a.y + r.y, v2 = a.z + r.z, v3 = a.w + r.w;
    if (X2EN) {
        float4 a2 = ((const float4*)(X2 + (row << 10)))[t];
        v0 += a2.x; v1 += a2.y; v2 += a2.z; v3 += a2.w;
    }
    float s = v0 + v1 + v2 + v3;
    float q = v0 * v0 + v1 * v1 + v2 * v2 + v3 * v3;
#pragma unroll
    for (int off = 32; off; off >>= 1) {
        s += __shfl_down(s, off);
        q += __shfl_down(q, off);
    }
    __shared__ float rs[4], rq[4];
    if ((t & 63) == 0) { rs[t >> 6] = s; rq[t >> 6] = q; }
    __syncthreads();
    s = rs[0] + rs[1] + rs[2] + rs[3];
    q = rq[0] + rq[1] + rq[2] + rq[3];
    float mean = s * (1.0f / 1024.0f);
    float var = q * (1.0f / 1024.0f) - mean * mean;
    float inv = rsqrtf(var + 1e-6f);
    float g0 = gamma[t * 4], g1 = gamma[t * 4 + 1], g2 = gamma[t * 4 + 2], g3 = gamma[t * 4 + 3];
    float b0 = beta[t * 4], b1 = beta[t * 4 + 1], b2 = beta[t * 4 + 2], b3 = beta[t * 4 + 3];
    float o0 = (v0 - mean) * inv * g0 + b0;
    float o1 = (v1 - mean) * inv * g1 + b1;
    float o2 = (v2 - mean) * inv * g2 + b2;
    float o3 = (v3 - mean) * inv * g3 + b3;
    float4 o; o.x = o0; o.y = o1; o.z = o2; o.w = o3;
    ((float4*)(outF + (row << 10)))[t] = o;
    if (WB) {
        us4 u;
        u[0] = f2bf(o0); u[1] = f2bf(o1); u[2] = f2bf(o2); u[3] = f2bf(o3);
        ((us4*)(outB + (row << 10)))[t] = u;
    }
}

extern "C" void kernel_launch(void* const* d_in, const int* in_sizes, int n_in,
                              void* d_out, int out_size, void* d_ws, size_t ws_size,
                              hipStream_t stream) {
    const float* x = (const float*)d_in[0];
    const float* enc = (const float*)d_in[1];
    const float* pad = (const float*)d_in[3];
    const float* wq1 = (const float*)d_in[4];  const float* bq1 = (const float*)d_in[5];
    const float* wk1 = (const float*)d_in[6];  const float* bk1 = (const float*)d_in[7];
    const float* wv1 = (const float*)d_in[8];  const float* bv1 = (const float*)d_in[9];
    const float* wo1 = (const float*)d_in[10]; const float* bo1 = (const float*)d_in[11];
    const float* wq2 = (const float*)d_in[12]; const float* bq2 = (const float*)d_in[13];
    const float* wk2 = (const float*)d_in[14]; const float* bk2 = (const float*)d_in[15];
    const float* wv2 = (const float*)d_in[16]; const float* bv2 = (const float*)d_in[17];
    const float* wo2 = (const float*)d_in[18]; const float* bo2 = (const float*)d_in[19];
    const float* wf1 = (const float*)d_in[20]; const float* bf1 = (const float*)d_in[21];
    const float* wf2 = (const float*)d_in[22]; const float* bf2 = (const float*)d_in[23];
    const float* g1 = (const float*)d_in[24]; const float* be1 = (const float*)d_in[25];
    const float* g2 = (const float*)d_in[26]; const float* be2 = (const float*)d_in[27];
    const float* g3 = (const float*)d_in[28]; const float* be3 = (const float*)d_in[29];

    float* out3 = (float*)d_out;
    float* aw1 = out3 + (size_t)NB * SEQ * DM;
    float* aw2 = aw1 + (size_t)NB * NH * SEQ * SEQ;

    char* ws = (char*)d_ws;
    size_t off = 0;
    auto take = [&](size_t n) { char* p = ws + off; off += (n + 255) & ~(size_t)255; return p; };
    const size_t SZ_SD_BF = (size_t)NB * SEQ * DM * 2;
    const size_t SZ_SD_F  = (size_t)NB * SEQ * DM * 4;
    const size_t SZ_DD_BF = (size_t)DM * DM * 2;

    // 8 square transposed weights MUST be contiguous in this order (castT8 indexes off wqkv1t):
    unsigned short* wqkv1t = (unsigned short*)take(3 * SZ_DD_BF);  // wq1,wk1,wv1
    unsigned short* wq2t   = (unsigned short*)take(SZ_DD_BF);
    unsigned short* wkv2t  = (unsigned short*)take(2 * SZ_DD_BF);  // wk2,wv2
    unsigned short* wo1t   = (unsigned short*)take(SZ_DD_BF);
    unsigned short* wo2t   = (unsigned short*)take(SZ_DD_BF);
    unsigned short* wf1t   = (unsigned short*)take((size_t)DM * DFFN * 2);
    unsigned short* wf2t   = (unsigned short*)take((size_t)DFFN * DM * 2);
    float* bqkv1 = (float*)take(3 * DM * 4);
    float* bkv2  = (float*)take(2 * DM * 4);
    unsigned short* xb    = (unsigned short*)take(SZ_SD_BF);
    unsigned short* encb  = (unsigned short*)take(SZ_SD_BF);
    unsigned short* qkv1b = (unsigned short*)take(3 * SZ_SD_BF);
    unsigned short* v1t   = (unsigned short*)take(SZ_SD_BF);
    unsigned short* qb    = (unsigned short*)take(SZ_SD_BF);
    unsigned short* kv2b  = (unsigned short*)take(2 * SZ_SD_BF);
    unsigned short* v2t   = (unsigned short*)take(SZ_SD_BF);
    unsigned short* ctx   = (unsigned short*)take(SZ_SD_BF);
    float* goutf  = (float*)take(SZ_SD_F);
    float* gout2f = (float*)take(SZ_SD_F);
    float* out1f  = (float*)take(SZ_SD_F);
    unsigned short* out1b = (unsigned short*)take(SZ_SD_BF);
    float* out2f  = (float*)take(SZ_SD_F);
    unsigned short* out2b = (unsigned short*)take(SZ_SD_BF);
    unsigned short* ffn1b = (unsigned short*)take((size_t)NB * SEQ * DFFN * 2);

    // ----- prep: 5 launches total -----
    {
        int n4 = NB * SEQ * DM / 4;
        dim3 gc((n4 + 255) / 256, 2);
        cast2_kernel<<<gc, 256, 0, stream>>>(x, enc, xb, encb, n4);
    }
    {
        P8 s;
        s.p[0] = wq1; s.p[1] = wk1; s.p[2] = wv1; s.p[3] = wq2;
        s.p[4] = wk2; s.p[5] = wv2; s.p[6] = wo1; s.p[7] = wo2;
        dim3 g8(DM / 64, DM / 64, 8);
        castT8_kernel<<<g8, 256, 0, stream>>>(s, wqkv1t);
    }
    castT_kernel<<<dim3(DFFN / 64, DM / 64), 256, 0, stream>>>(wf1, wf1t, DM, DFFN);
    castT_kernel<<<dim3(DM / 64, DFFN / 64), 256, 0, stream>>>(wf2, wf2t, DFFN, DM);
    biaspack_kernel<<<20, 256, 0, stream>>>(bq1, bk1, bv1, bk2, bv2, bqkv1, bkv2);

    const int M = NB * SEQ;
    dim3 gQKV(3 * DM / 128, M / 128);
    dim3 gKV(2 * DM / 128, M / 128);
    dim3 gDD64(DM / 128, M / 64);
    dim3 gDF(DFFN / 128, M / 128);
    dim3 gF2(DM / 128, M / 128, 2);   // FFN2 split-K

    // ---- MHA1 (self, causal) ----
    gemm_kernel<128, 128, 32, 1, 0, 1, 0, 1><<<gQKV, 256, 0, stream>>>(xb, wqkv1t, bqkv1, qkv1b, nullptr, nullptr, v1t, 2048, M, 3 * DM, DM);
    attn_kernel<1><<<4096, 256, 0, stream>>>(qkv1b, 3 * DM, qkv1b + DM, 3 * DM, v1t, nullptr, aw1, ctx);
    gemm_kernel<64, 128, 64, 1, 0, 0, 1, 0><<<gDD64, 256, 0, stream>>>(ctx, wo1t, bo1, nullptr, goutf, nullptr, nullptr, 0, M, DM, DM);
    ln_kernel<1, 0><<<M, 256, 0, stream>>>(goutf, nullptr, x, g1, be1, out1f, out1b);

    // ---- MHA2 (cross, padding mask) ----
    gemm_kernel<64, 128, 64, 1, 0, 1, 0, 0><<<gDD64, 256, 0, stream>>>(out1b, wq2t, bq2, qb, nullptr, nullptr, nullptr, 0, M, DM, DM);
    gemm_kernel<128, 128, 32, 1, 0, 1, 0, 1><<<gKV, 256, 0, stream>>>(encb, wkv2t, bkv2, kv2b, nullptr, nullptr, v2t, 1024, M, 2 * DM, DM);
    attn_kernel<0><<<4096, 256, 0, stream>>>(qb, DM, kv2b, 2 * DM, v2t, pad, aw2, ctx);
    gemm_kernel<64, 128, 64, 1, 0, 0, 1, 0><<<gDD64, 256, 0, stream>>>(ctx, wo2t, bo2, nullptr, goutf, nullptr, nullptr, 0, M, DM, DM);
    ln_kernel<1, 0><<<M, 256, 0, stream>>>(goutf, nullptr, out1f, g2, be2, out2f, out2b);

    // ---- FFN ----
    gemm_kernel<128, 128, 32, 1, 1, 1, 0, 0><<<gDF, 256, 0, stream>>>(out2b, wf1t, bf1, ffn1b, nullptr, nullptr, nullptr, 0, M, DFFN, DM);
    gemm_kernel<128, 128, 32, 2, 0, 0, 1, 0><<<gF2, 256, 0, stream>>>(ffn1b, wf2t, bf2, nullptr, goutf, gout2f, nullptr, 0, M, DM, DFFN);
    ln_kernel<0, 1><<<M, 256, 0, stream>>>(goutf, gout2f, out2f, g3, be3, out3, nullptr);
}

// Round 6
// 579.335 us; speedup vs baseline: 2.4000x; 1.1089x over previous
//
#include <hip/hip_runtime.h>

#define NB 4
#define SEQ 1024
#define DM 1024
#define NH 16
#define DEP 64
#define DFFN 4096

typedef __attribute__((ext_vector_type(8))) short short8;
typedef __attribute__((ext_vector_type(4))) float f32x4;
typedef __attribute__((ext_vector_type(4))) unsigned short us4;

__device__ __forceinline__ unsigned short f2bf(float f) {
    union { float f; unsigned int u; } v; v.f = f;
    unsigned int u = v.u;
    return (unsigned short)((u + 0x7FFFu + ((u >> 16) & 1u)) >> 16);
}

__device__ __forceinline__ void gload16(const void* g, void* l) {
    __builtin_amdgcn_global_load_lds((const __attribute__((address_space(1))) unsigned int*)g,
                                     (__attribute__((address_space(3))) unsigned int*)l, 16, 0, 0);
}

// ---------------- dual cast f32 -> bf16 (x and enc in one launch) ----------------
__global__ __launch_bounds__(256) void cast2_kernel(const float* __restrict__ a,
                                                    const float* __restrict__ b,
                                                    unsigned short* __restrict__ oa,
                                                    unsigned short* __restrict__ ob, int n4) {
    int i = blockIdx.x * 256 + threadIdx.x;
    const float* in = blockIdx.y ? b : a;
    unsigned short* out = blockIdx.y ? ob : oa;
    if (i < n4) {
        float4 f = ((const float4*)in)[i];
        us4 u;
        u[0] = f2bf(f.x); u[1] = f2bf(f.y); u[2] = f2bf(f.z); u[3] = f2bf(f.w);
        ((us4*)out)[i] = u;
    }
}

// ---------------- transpose-cast: W (RxC f32) -> Wt (CxR bf16) ----------------
__global__ __launch_bounds__(256) void castT_kernel(const float* __restrict__ in,
                                                    unsigned short* __restrict__ out,
                                                    int R, int C) {
    __shared__ float tile[64][65];
    const int t = threadIdx.x;
    const int c0 = blockIdx.x * 64, r0 = blockIdx.y * 64;
#pragma unroll
    for (int p = 0; p < 4; ++p) {
        int r = p * 16 + (t >> 4), c = (t & 15) * 4;
        float4 f = *(const float4*)(in + (size_t)(r0 + r) * C + c0 + c);
        tile[r][c] = f.x; tile[r][c + 1] = f.y; tile[r][c + 2] = f.z; tile[r][c + 3] = f.w;
    }
    __syncthreads();
#pragma unroll
    for (int p = 0; p < 4; ++p) {
        int n = p * 16 + (t >> 4), k = (t & 15) * 4;
        us4 u;
#pragma unroll
        for (int j = 0; j < 4; ++j) u[j] = f2bf(tile[k + j][n]);
        *(us4*)(out + (size_t)(c0 + n) * R + r0 + k) = u;
    }
}

// ---------------- batched transpose-cast for 8 DMxDM weights ----------------
struct P8 { const float* p[8]; };
__global__ __launch_bounds__(256) void castT8_kernel(P8 srcs, unsigned short* __restrict__ dstbase) {
    __shared__ float tile[64][65];
    const float* in = srcs.p[blockIdx.z];
    unsigned short* out = dstbase + (size_t)blockIdx.z * DM * DM;
    const int t = threadIdx.x;
    const int c0 = blockIdx.x * 64, r0 = blockIdx.y * 64;
#pragma unroll
    for (int p = 0; p < 4; ++p) {
        int r = p * 16 + (t >> 4), c = (t & 15) * 4;
        float4 f = *(const float4*)(in + (size_t)(r0 + r) * DM + c0 + c);
        tile[r][c] = f.x; tile[r][c + 1] = f.y; tile[r][c + 2] = f.z; tile[r][c + 3] = f.w;
    }
    __syncthreads();
#pragma unroll
    for (int p = 0; p < 4; ++p) {
        int n = p * 16 + (t >> 4), k = (t & 15) * 4;
        us4 u;
#pragma unroll
        for (int j = 0; j < 4; ++j) u[j] = f2bf(tile[k + j][n]);
        *(us4*)(out + (size_t)(c0 + n) * DM + r0 + k) = u;
    }
}

// ---------------- bias concat pack ----------------
__global__ __launch_bounds__(256) void biaspack_kernel(const float* __restrict__ bq1,
                                                       const float* __restrict__ bk1,
                                                       const float* __restrict__ bv1,
                                                       const float* __restrict__ bk2,
                                                       const float* __restrict__ bv2,
                                                       float* __restrict__ bqkv1,
                                                       float* __restrict__ bkv2) {
    int i = blockIdx.x * 256 + threadIdx.x;
    if (i < 1024) bqkv1[i] = bq1[i];
    else if (i < 2048) bqkv1[i] = bk1[i - 1024];
    else if (i < 3072) bqkv1[i] = bv1[i - 2048];
    else if (i < 4096) bkv2[i - 3072] = bk2[i - 3072];
    else if (i < 5120) bkv2[i - 3072] = bv2[i - 4096];
}

// ---------------- m97-style bf16 GEMM: C = A(MxK) @ Wt^T + bias ----------------
template <int BM, int BN, int BK, int KSPLIT, int RELU, int WB, int WF, int WVT>
__global__ __launch_bounds__(256) void gemm_kernel(const unsigned short* __restrict__ A,
                                                   const unsigned short* __restrict__ Wt,
                                                   const float* __restrict__ bias,
                                                   unsigned short* __restrict__ Cb,
                                                   float* __restrict__ Cf,
                                                   float* __restrict__ Cf2,
                                                   unsigned short* __restrict__ Vt,
                                                   int vstart,
                                                   int M, int N, int K) {
    constexpr int AM = BM / 32;
    constexpr int KS = BK / 32;
    constexpr int LPR = BK / 8;
    constexpr int RPI = 64 / LPR;
    constexpr int AR = (BM / 4) / RPI;
    constexpr int BR = (BN / 4) / RPI;
    __shared__ unsigned short As[BM * BK];
    __shared__ unsigned short Bs[BN * BK];
    const int t = threadIdx.x;
    const int lane = t & 63, w = t >> 6;
    const int m0 = blockIdx.y * BM, n0 = blockIdx.x * BN;
    const int wm = (w >> 1) * (BM / 2), wn = (w & 1) * (BN / 2);
    const int lr = lane & 15, g = lane >> 4, kb = g * 8;
    const int srow = lane / LPR, scol = (lane % LPR) * 8;
    const int kofs = (KSPLIT == 2 && blockIdx.z) ? K / 2 : 0;
    const int Keff = (KSPLIT == 2) ? K / 2 : K;

    f32x4 acc[AM][4];
#pragma unroll
    for (int a = 0; a < AM; ++a)
#pragma unroll
        for (int b = 0; b < 4; ++b)
#pragma unroll
            for (int j = 0; j < 4; ++j) acc[a][b][j] = 0.f;

    for (int kt = 0; kt < Keff; kt += BK) {
        __syncthreads();
#pragma unroll
        for (int ia = 0; ia < AR; ++ia) {
            int rb = w * (BM / 4) + ia * RPI;
            gload16(A + (size_t)(m0 + rb + srow) * K + kofs + kt + scol, As + rb * BK);
        }
#pragma unroll
        for (int ib = 0; ib < BR; ++ib) {
            int rb = w * (BN / 4) + ib * RPI;
            gload16(Wt + (size_t)(n0 + rb + srow) * K + kofs + kt + scol, Bs + rb * BK);
        }
        __syncthreads();

        short8 af[AM][KS], bfr[4][KS];
#pragma unroll
        for (int i = 0; i < AM; ++i)
#pragma unroll
            for (int ks = 0; ks < KS; ++ks)
                af[i][ks] = *(const short8*)&As[(wm + i * 16 + lr) * BK + ks * 32 + kb];
#pragma unroll
        for (int i = 0; i < 4; ++i)
#pragma unroll
            for (int ks = 0; ks < KS; ++ks)
                bfr[i][ks] = *(const short8*)&Bs[(wn + i * 16 + lr) * BK + ks * 32 + kb];
#pragma unroll
        for (int ks = 0; ks < KS; ++ks)
#pragma unroll
            for (int am = 0; am < AM; ++am)
#pragma unroll
                for (int bn = 0; bn < 4; ++bn)
                    acc[am][bn] = __builtin_amdgcn_mfma_f32_16x16x32_bf16(af[am][ks], bfr[bn][ks], acc[am][bn], 0, 0, 0);
    }

    float* cfo = (KSPLIT == 2 && blockIdx.z) ? Cf2 : Cf;
    const bool addb = bias && (KSPLIT == 1 || blockIdx.z == 0);
#pragma unroll
    for (int am = 0; am < AM; ++am) {
#pragma unroll
        for (int bn = 0; bn < 4; ++bn) {
            int col = n0 + wn + bn * 16 + lr;
            float bv = addb ? bias[col] : 0.f;
            int rowb = m0 + wm + am * 16 + g * 4;
            float vv[4];
#pragma unroll
            for (int i = 0; i < 4; ++i) {
                float v = acc[am][bn][i] + bv;
                if (RELU) v = v > 0.f ? v : 0.f;
                vv[i] = v;
                if (WF) cfo[(size_t)(rowb + i) * N + col] = v;
                if (WB) Cb[(size_t)(rowb + i) * N + col] = f2bf(v);
            }
            if (WVT && col >= vstart) {
                int h = (col - vstart) >> 6, dep = (col - vstart) & 63;
                int b = rowb >> 10, kpos = rowb & 1023;
                us4 u;
#pragma unroll
                for (int i = 0; i < 4; ++i) u[i] = f2bf(vv[i]);
                *(us4*)(Vt + ((size_t)(b * NH + h) * DEP + dep) * SEQ + kpos) = u;
            }
        }
    }
}

// ---------------- fused attention v3: 32 q-rows/block, gload16+swizzled K, swapped QK^T ----------------
// grid 2048: bh = (id&7) + ((id>>8)<<3) [XCD-bijective], qt = (id>>3)&31.
// Lane holds S^T: q = q0 + p*16 + lr, k = kc*256 + w*64 + bn*16 + g*4 + i.
template <int CAUSAL>
__global__ __launch_bounds__(256, 2) void attn_kernel(const unsigned short* __restrict__ Q, int ldq,
                                                      const unsigned short* __restrict__ Kp, int ldk,
                                                      const unsigned short* __restrict__ Vt,
                                                      const float* __restrict__ pad,
                                                      float* __restrict__ aw,
                                                      unsigned short* __restrict__ ctx) {
    __shared__ unsigned short Ks[256 * 64];   // 32 KB, linear rows (128 B), source-swizzled
    __shared__ unsigned short Pch[32 * 256];  // 16 KB, XOR-swizzled
    __shared__ float redm[4][32];
    __shared__ float reds[4][32];
    const int t = threadIdx.x, lane = t & 63, w = t >> 6;
    const int lr = lane & 15, g = lane >> 4;
    const int id = blockIdx.x;
    const int bh = (id & 7) + ((id >> 8) << 3);
    const int qt = (id >> 3) & 31;
    const int q0 = qt * 32;
    const int b = bh >> 4, h = bh & 15;
    const size_t qbase = (size_t)b * SEQ * ldq + (size_t)h * DEP;
    const size_t kbase = (size_t)b * SEQ * ldk + (size_t)h * DEP;
    const int kcmax = CAUSAL ? ((q0 + 16) >> 8) + 1 : 4;

    // Q fragments (B-operand): row q0+p*16+lr, depth ks*32+g*8
    short8 aq[2][2];
#pragma unroll
    for (int p = 0; p < 2; ++p)
#pragma unroll
        for (int ks = 0; ks < 2; ++ks)
            aq[p][ks] = *(const short8*)(Q + qbase + (size_t)(q0 + p * 16 + lr) * ldq + ks * 32 + g * 8);

    f32x4 acc[2][4][4];
#pragma unroll
    for (int p = 0; p < 2; ++p)
#pragma unroll
        for (int a = 0; a < 4; ++a)
#pragma unroll
            for (int b2 = 0; b2 < 4; ++b2)
#pragma unroll
                for (int j = 0; j < 4; ++j) acc[p][a][b2][j] = 0.f;

    // staging lane decomposition: 8 rows x 8 slots of 16B per issue; source slot pre-swizzled
    const int srow = lane >> 3;
    const int sslot = (lane & 7) ^ srow;

    // ---- QK^T (swapped: mfma(K, Q) -> S^T) ----
#pragma unroll
    for (int kc = 0; kc < 4; ++kc) {
        if (kc < kcmax) {
            __syncthreads();
#pragma unroll
            for (int i = 0; i < 8; ++i) {
                int rb = w * 64 + i * 8;
                gload16(Kp + kbase + (size_t)(kc * 256 + rb + srow) * ldk + sslot * 8,
                        Ks + rb * 64);
            }
            __syncthreads();
#pragma unroll
            for (int ks = 0; ks < 2; ++ks)
#pragma unroll
                for (int bn = 0; bn < 4; ++bn) {
                    int row = w * 64 + bn * 16 + lr;
                    short8 bk = *(const short8*)((const char*)Ks + row * 128 +
                                                 ((ks * 64 + g * 16) ^ ((lr & 7) << 4)));
                    acc[0][kc][bn] = __builtin_amdgcn_mfma_f32_16x16x32_bf16(bk, aq[0][ks], acc[0][kc][bn], 0, 0, 0);
                    acc[1][kc][bn] = __builtin_amdgcn_mfma_f32_16x16x32_bf16(bk, aq[1][ks], acc[1][kc][bn], 0, 0, 0);
                }
        }
    }

    // ---- scale + masks + row max ----
    float mrow[2] = {-1e30f, -1e30f};
#pragma unroll
    for (int kc = 0; kc < 4; ++kc) {
        if (kc < kcmax) {
#pragma unroll
            for (int bn = 0; bn < 4; ++bn) {
                int k4 = kc * 256 + w * 64 + bn * 16 + g * 4;
                f32x4 pv = {0.f, 0.f, 0.f, 0.f};
                if (pad) pv = *(const f32x4*)(pad + (size_t)b * SEQ + k4);
#pragma unroll
                for (int p = 0; p < 2; ++p) {
                    int q = q0 + p * 16 + lr;
#pragma unroll
                    for (int i = 0; i < 4; ++i) {
                        float v = acc[p][kc][bn][i] * 0.125f + pv[i] * -1e9f;
                        if (CAUSAL && (k4 + i) > q) v = -1e30f;
                        acc[p][kc][bn][i] = v;
                        mrow[p] = fmaxf(mrow[p], v);
                    }
                }
            }
        }
    }
#pragma unroll
    for (int p = 0; p < 2; ++p) {
        mrow[p] = fmaxf(mrow[p], __shfl_xor(mrow[p], 16));
        mrow[p] = fmaxf(mrow[p], __shfl_xor(mrow[p], 32));
    }
    if (lane < 16) { redm[w][lr] = mrow[0]; redm[w][16 + lr] = mrow[1]; }
    __syncthreads();
    float Mv[2];
#pragma unroll
    for (int p = 0; p < 2; ++p)
        Mv[p] = fmaxf(fmaxf(redm[0][p * 16 + lr], redm[1][p * 16 + lr]),
                      fmaxf(redm[2][p * 16 + lr], redm[3][p * 16 + lr]));

    // ---- exp + row sum ----
    float srw[2] = {0.f, 0.f};
#pragma unroll
    for (int kc = 0; kc < 4; ++kc) {
        if (kc < kcmax) {
#pragma unroll
            for (int p = 0; p < 2; ++p)
#pragma unroll
                for (int bn = 0; bn < 4; ++bn)
#pragma unroll
                    for (int i = 0; i < 4; ++i) {
                        float e = __expf(acc[p][kc][bn][i] - Mv[p]);
                        acc[p][kc][bn][i] = e;
                        srw[p] += e;
                    }
        }
    }
#pragma unroll
    for (int p = 0; p < 2; ++p) {
        srw[p] += __shfl_xor(srw[p], 16);
        srw[p] += __shfl_xor(srw[p], 32);
    }
    if (lane < 16) { reds[w][lr] = srw[0]; reds[w][16 + lr] = srw[1]; }
    __syncthreads();
    float inv[2];
#pragma unroll
    for (int p = 0; p < 2; ++p)
        inv[p] = 1.0f / (reds[0][p * 16 + lr] + reds[1][p * 16 + lr] +
                         reds[2][p * 16 + lr] + reds[3][p * 16 + lr]);

    // ---- aw writes: float4 per (p,kc,bn), zero-fill beyond kcmax ----
#pragma unroll
    for (int p = 0; p < 2; ++p) {
        float* awrow = aw + ((size_t)bh * SEQ + q0 + p * 16 + lr) * SEQ;
#pragma unroll
        for (int kc = 0; kc < 4; ++kc)
#pragma unroll
            for (int bn = 0; bn < 4; ++bn) {
                f32x4 o = {0.f, 0.f, 0.f, 0.f};
                if (kc < kcmax) {
#pragma unroll
                    for (int i = 0; i < 4; ++i) o[i] = acc[p][kc][bn][i] * inv[p];
                }
                *(f32x4*)(awrow + kc * 256 + w * 64 + bn * 16 + g * 4) = o;
            }
    }

    // ---- PV: per-kc P-chunk via swizzled LDS; wave w owns d-tile w*16; Vt reads shared across p ----
    f32x4 acc2[2];
#pragma unroll
    for (int p = 0; p < 2; ++p)
#pragma unroll
        for (int j = 0; j < 4; ++j) acc2[p][j] = 0.f;
    char* pch = (char*)Pch;
    const int sw = (lr & 7) << 4;
#pragma unroll
    for (int kc = 0; kc < 4; ++kc) {
        if (kc < kcmax) {
            __syncthreads();
#pragma unroll
            for (int p = 0; p < 2; ++p)
#pragma unroll
                for (int bn = 0; bn < 4; ++bn) {
                    us4 u;
#pragma unroll
                    for (int i = 0; i < 4; ++i) u[i] = f2bf(acc[p][kc][bn][i] * inv[p]);
                    *(us4*)(pch + (p * 16 + lr) * 512 + ((w * 128 + bn * 32 + g * 8) ^ sw)) = u;
                }
            __syncthreads();
#pragma unroll
            for (int ks = 0; ks < 8; ++ks) {
                short8 bf = *(const short8*)(Vt + ((size_t)bh * DEP + w * 16 + lr) * SEQ + kc * 256 + ks * 32 + g * 8);
#pragma unroll
                for (int p = 0; p < 2; ++p) {
                    short8 af = *(const short8*)(pch + (p * 16 + lr) * 512 + ((ks * 64 + g * 16) ^ sw));
                    acc2[p] = __builtin_amdgcn_mfma_f32_16x16x32_bf16(af, bf, acc2[p], 0, 0, 0);
                }
            }
        }
    }
#pragma unroll
    for (int p = 0; p < 2; ++p)
#pragma unroll
        for (int i = 0; i < 4; ++i)
            ctx[((size_t)b * SEQ + q0 + p * 16 + g * 4 + i) * DM + h * DEP + w * 16 + lr] = f2bf(acc2[p][i]);
}

// ---------------- residual + layernorm: out = LN(X [+ X2] + R) ----------------
template <int WB, int X2EN>
__global__ __launch_bounds__(256) void ln_kernel(const float* __restrict__ X,
                                                 const float* __restrict__ X2,
                                                 const float* __restrict__ R,
                                                 const float* __restrict__ gamma,
                                                 const float* __restrict__ beta,
                                                 float* __restrict__ outF,
                                                 unsigned short* __restrict__ outB) {
    size_t row = blockIdx.x;
    const int t = threadIdx.x;
    float4 a = ((const float4*)(X + (row << 10)))[t];
    float4 r = ((const float4*)(R + (row << 10)))[t];
    float v0 = a.x + r.x, v1 = a.y + r.y, v2 = a.z + r.z, v3 = a.w + r.w;
    if (X2EN) {
        float4 a2 = ((const float4*)(X2 + (row << 10)))[t];
        v0 += a2.x; v1 += a2.y; v2 += a2.z; v3 += a2.w;
    }
    float s = v0 + v1 + v2 + v3;
    float q = v0 * v0 + v1 * v1 + v2 * v2 + v3 * v3;
#pragma unroll
    for (int off = 32; off; off >>= 1) {
        s += __shfl_down(s, off);
        q += __shfl_down(q, off);
    }
    __shared__ float rs[4], rq[4];
    if ((t & 63) == 0) { rs[t >> 6] = s; rq[t >> 6] = q; }
    __syncthreads();
    s = rs[0] + rs[1] + rs[2] + rs[3];
    q = rq[0] + rq[1] + rq[2] + rq[3];
    float mean = s * (1.0f / 1024.0f);
    float var = q * (1.0f / 1024.0f) - mean * mean;
    float inv = rsqrtf(var + 1e-6f);
    float g0 = gamma[t * 4], g1 = gamma[t * 4 + 1], g2 = gamma[t * 4 + 2], g3 = gamma[t * 4 + 3];
    float b0 = beta[t * 4], b1 = beta[t * 4 + 1], b2 = beta[t * 4 + 2], b3 = beta[t * 4 + 3];
    float o0 = (v0 - mean) * inv * g0 + b0;
    float o1 = (v1 - mean) * inv * g1 + b1;
    float o2 = (v2 - mean) * inv * g2 + b2;
    float o3 = (v3 - mean) * inv * g3 + b3;
    float4 o; o.x = o0; o.y = o1; o.z = o2; o.w = o3;
    ((float4*)(outF + (row << 10)))[t] = o;
    if (WB) {
        us4 u;
        u[0] = f2bf(o0); u[1] = f2bf(o1); u[2] = f2bf(o2); u[3] = f2bf(o3);
        ((us4*)(outB + (row << 10)))[t] = u;
    }
}

extern "C" void kernel_launch(void* const* d_in, const int* in_sizes, int n_in,
                              void* d_out, int out_size, void* d_ws, size_t ws_size,
                              hipStream_t stream) {
    const float* x = (const float*)d_in[0];
    const float* enc = (const float*)d_in[1];
    const float* pad = (const float*)d_in[3];
    const float* wq1 = (const float*)d_in[4];  const float* bq1 = (const float*)d_in[5];
    const float* wk1 = (const float*)d_in[6];  const float* bk1 = (const float*)d_in[7];
    const float* wv1 = (const float*)d_in[8];  const float* bv1 = (const float*)d_in[9];
    const float* wo1 = (const float*)d_in[10]; const float* bo1 = (const float*)d_in[11];
    const float* wq2 = (const float*)d_in[12]; const float* bq2 = (const float*)d_in[13];
    const float* wk2 = (const float*)d_in[14]; const float* bk2 = (const float*)d_in[15];
    const float* wv2 = (const float*)d_in[16]; const float* bv2 = (const float*)d_in[17];
    const float* wo2 = (const float*)d_in[18]; const float* bo2 = (const float*)d_in[19];
    const float* wf1 = (const float*)d_in[20]; const float* bf1 = (const float*)d_in[21];
    const float* wf2 = (const float*)d_in[22]; const float* bf2 = (const float*)d_in[23];
    const float* g1 = (const float*)d_in[24]; const float* be1 = (const float*)d_in[25];
    const float* g2 = (const float*)d_in[26]; const float* be2 = (const float*)d_in[27];
    const float* g3 = (const float*)d_in[28]; const float* be3 = (const float*)d_in[29];

    float* out3 = (float*)d_out;
    float* aw1 = out3 + (size_t)NB * SEQ * DM;
    float* aw2 = aw1 + (size_t)NB * NH * SEQ * SEQ;

    char* ws = (char*)d_ws;
    size_t off = 0;
    auto take = [&](size_t n) { char* p = ws + off; off += (n + 255) & ~(size_t)255; return p; };
    const size_t SZ_SD_BF = (size_t)NB * SEQ * DM * 2;
    const size_t SZ_SD_F  = (size_t)NB * SEQ * DM * 4;
    const size_t SZ_DD_BF = (size_t)DM * DM * 2;

    unsigned short* wqkv1t = (unsigned short*)take(3 * SZ_DD_BF);
    unsigned short* wq2t   = (unsigned short*)take(SZ_DD_BF);
    unsigned short* wkv2t  = (unsigned short*)take(2 * SZ_DD_BF);
    unsigned short* wo1t   = (unsigned short*)take(SZ_DD_BF);
    unsigned short* wo2t   = (unsigned short*)take(SZ_DD_BF);
    unsigned short* wf1t   = (unsigned short*)take((size_t)DM * DFFN * 2);
    unsigned short* wf2t   = (unsigned short*)take((size_t)DFFN * DM * 2);
    float* bqkv1 = (float*)take(3 * DM * 4);
    float* bkv2  = (float*)take(2 * DM * 4);
    unsigned short* xb    = (unsigned short*)take(SZ_SD_BF);
    unsigned short* encb  = (unsigned short*)take(SZ_SD_BF);
    unsigned short* qkv1b = (unsigned short*)take(3 * SZ_SD_BF);
    unsigned short* v1t   = (unsigned short*)take(SZ_SD_BF);
    unsigned short* qb    = (unsigned short*)take(SZ_SD_BF);
    unsigned short* kv2b  = (unsigned short*)take(2 * SZ_SD_BF);
    unsigned short* v2t   = (unsigned short*)take(SZ_SD_BF);
    unsigned short* ctx   = (unsigned short*)take(SZ_SD_BF);
    float* goutf  = (float*)take(SZ_SD_F);
    float* gout2f = (float*)take(SZ_SD_F);
    float* out1f  = (float*)take(SZ_SD_F);
    unsigned short* out1b = (unsigned short*)take(SZ_SD_BF);
    float* out2f  = (float*)take(SZ_SD_F);
    unsigned short* out2b = (unsigned short*)take(SZ_SD_BF);
    unsigned short* ffn1b = (unsigned short*)take((size_t)NB * SEQ * DFFN * 2);

    {
        int n4 = NB * SEQ * DM / 4;
        dim3 gc((n4 + 255) / 256, 2);
        cast2_kernel<<<gc, 256, 0, stream>>>(x, enc, xb, encb, n4);
    }
    {
        P8 s;
        s.p[0] = wq1; s.p[1] = wk1; s.p[2] = wv1; s.p[3] = wq2;
        s.p[4] = wk2; s.p[5] = wv2; s.p[6] = wo1; s.p[7] = wo2;
        dim3 g8(DM / 64, DM / 64, 8);
        castT8_kernel<<<g8, 256, 0, stream>>>(s, wqkv1t);
    }
    castT_kernel<<<dim3(DFFN / 64, DM / 64), 256, 0, stream>>>(wf1, wf1t, DM, DFFN);
    castT_kernel<<<dim3(DM / 64, DFFN / 64), 256, 0, stream>>>(wf2, wf2t, DFFN, DM);
    biaspack_kernel<<<20, 256, 0, stream>>>(bq1, bk1, bv1, bk2, bv2, bqkv1, bkv2);

    const int M = NB * SEQ;
    dim3 gQKV(3 * DM / 128, M / 128);
    dim3 gKV(2 * DM / 128, M / 128);
    dim3 gDD64(DM / 128, M / 64);
    dim3 gDF(DFFN / 128, M / 128);
    dim3 gF2(DM / 128, M / 128, 2);

    // ---- MHA1 (self, causal) ----
    gemm_kernel<128, 128, 32, 1, 0, 1, 0, 1><<<gQKV, 256, 0, stream>>>(xb, wqkv1t, bqkv1, qkv1b, nullptr, nullptr, v1t, 2048, M, 3 * DM, DM);
    attn_kernel<1><<<2048, 256, 0, stream>>>(qkv1b, 3 * DM, qkv1b + DM, 3 * DM, v1t, nullptr, aw1, ctx);
    gemm_kernel<64, 128, 64, 1, 0, 0, 1, 0><<<gDD64, 256, 0, stream>>>(ctx, wo1t, bo1, nullptr, goutf, nullptr, nullptr, 0, M, DM, DM);
    ln_kernel<1, 0><<<M, 256, 0, stream>>>(goutf, nullptr, x, g1, be1, out1f, out1b);

    // ---- MHA2 (cross, padding mask) ----
    gemm_kernel<64, 128, 64, 1, 0, 1, 0, 0><<<gDD64, 256, 0, stream>>>(out1b, wq2t, bq2, qb, nullptr, nullptr, nullptr, 0, M, DM, DM);
    gemm_kernel<128, 128, 32, 1, 0, 1, 0, 1><<<gKV, 256, 0, stream>>>(encb, wkv2t, bkv2, kv2b, nullptr, nullptr, v2t, 1024, M, 2 * DM, DM);
    attn_kernel<0><<<2048, 256, 0, stream>>>(qb, DM, kv2b, 2 * DM, v2t, pad, aw2, ctx);
    gemm_kernel<64, 128, 64, 1, 0, 0, 1, 0><<<gDD64, 256, 0, stream>>>(ctx, wo2t, bo2, nullptr, goutf, nullptr, nullptr, 0, M, DM, DM);
    ln_kernel<1, 0><<<M, 256, 0, stream>>>(goutf, nullptr, out1f, g2, be2, out2f, out2b);

    // ---- FFN ----
    gemm_kernel<128, 128, 32, 1, 1, 1, 0, 0><<<gDF, 256, 0, stream>>>(out2b, wf1t, bf1, ffn1b, nullptr, nullptr, nullptr, 0, M, DFFN, DM);
    gemm_kernel<128, 128, 32, 2, 0, 0, 1, 0><<<gF2, 256, 0, stream>>>(ffn1b, wf2t, bf2, nullptr, goutf, gout2f, nullptr, 0, M, DM, DFFN);
    ln_kernel<0, 1><<<M, 256, 0, stream>>>(goutf, gout2f, out2f, g3, be3, out3, nullptr);
}